// Round 6
// baseline (2711.743 us; speedup 1.0000x reference)
//
#include <hip/hip_runtime.h>

typedef unsigned short u16;
typedef __bf16 bf16x8 __attribute__((ext_vector_type(8)));
typedef float f32x4 __attribute__((ext_vector_type(4)));

#define NB 32
#define ND 768
#define NTOK 197
#define NROWS (NB * NTOK)   /* 6304 */
#define NPATCH 196
#define PROWS (NB * NPATCH) /* 6272 */
#define NHD 12
#define NDFF 3072
#define NLAY 12
#define NQKV 2304

// RNE float->bf16
static __device__ __forceinline__ u16 f2b(float f) {
  unsigned int u = __builtin_bit_cast(unsigned int, f);
  unsigned int r = u + 0x7FFFu + ((u >> 16) & 1u);
  return (u16)(r >> 16);
}

static __device__ __forceinline__ float wsum(float v) {
#pragma unroll
  for (int off = 32; off > 0; off >>= 1) v += __shfl_xor(v, off);
  return v;
}

static __device__ __forceinline__ void stage16(const u16* g, u16* l) {
  __builtin_amdgcn_global_load_lds((const __attribute__((address_space(1))) void*)g,
                                   (__attribute__((address_space(3))) void*)l, 16, 0, 0);
}

// ---------------- positional encoding table [197][768] ----------------
__global__ void pe_kernel(float* __restrict__ pe) {
  int idx = blockIdx.x * 256 + threadIdx.x;
  if (idx >= NTOK * ND) return;
  int t = idx / ND, d = idx % ND;
  int i = d & ~1;
  float e = (2.0f * (float)i) / (float)ND;
  float denom = powf(10000.0f, e);
  float ang = (float)t / denom;
  pe[idx] = (d & 1) ? cosf(ang) : sinf(ang);
}

// ---------------- BN + unfold-order patchify -> bf16 [6272][768] -------
__global__ void patch_kernel(const float* __restrict__ x,
                             const float* __restrict__ bng, const float* __restrict__ bnb,
                             const float* __restrict__ bnm, const float* __restrict__ bnv,
                             u16* __restrict__ out) {
  int idx = blockIdx.x * 256 + threadIdx.x;
  if (idx >= PROWS * ND) return;
  int row = idx / ND, col = idx % ND;
  int b = row / NPATCH, s = row % NPATCH;
  int ph = s / 14, pw = s % 14;
  int c = col / 256, rr = col % 256;
  int py = rr / 16, px = rr % 16;
  float v = x[(((size_t)(b * 3 + c) * 224) + ph * 16 + py) * 224 + pw * 16 + px];
  v = (v - bnm[c]) * rsqrtf(bnv[c] + 1e-5f) * bng[c] + bnb[c];
  out[idx] = f2b(v);
}

// ---------------- cls token row (t=0) + pe[0] --------------------------
__global__ void cls_kernel(const float* __restrict__ cls_w, const float* __restrict__ pe,
                           float* __restrict__ h, u16* __restrict__ hb) {
  int idx = blockIdx.x * 256 + threadIdx.x;
  if (idx >= NB * ND) return;
  int b = idx / ND, d = idx % ND;
  float v = cls_w[d] + pe[d];
  size_t o = (size_t)(b * NTOK) * ND + d;
  h[o] = v;
  hb[o] = f2b(v);
}

// ---------------- fp32 [R][C] -> bf16 [C][R] transpose-convert ---------
__global__ __launch_bounds__(256) void transpose_cvt(const float* __restrict__ src,
                                                     u16* __restrict__ dst, int R, int C) {
  __shared__ float tile[32][33];
  int tx = threadIdx.x, ty = threadIdx.y;
  int c0 = blockIdx.x * 32, r0 = blockIdx.y * 32;
#pragma unroll
  for (int i = ty; i < 32; i += 8) {
    int r = r0 + i, c = c0 + tx;
    tile[i][tx] = (r < R && c < C) ? src[(size_t)r * C + c] : 0.f;
  }
  __syncthreads();
#pragma unroll
  for (int i = ty; i < 32; i += 8) {
    int c = c0 + i, r = r0 + tx;
    if (r < R && c < C) dst[(size_t)c * R + r] = f2b(tile[tx][i]);
  }
}

// -------- all 5 weight transposes of one layer in a single launch ------
__global__ __launch_bounds__(256) void transpose_layer(
    const float* __restrict__ Wq, const float* __restrict__ Wk, const float* __restrict__ Wv,
    const float* __restrict__ f1, const float* __restrict__ f2,
    u16* __restrict__ wqkvt, u16* __restrict__ fc1t, u16* __restrict__ fc2t) {
  int idx = blockIdx.x;
  const float* src;
  u16* dst;
  int C, R, rt, ct;
  if (idx < 1728) {
    int z = idx / 576, loc = idx % 576;
    src = z == 0 ? Wq : (z == 1 ? Wk : Wv);
    dst = wqkvt + (size_t)z * ND * ND;
    R = 768; C = 768; rt = loc / 24; ct = loc % 24;
  } else if (idx < 4032) {
    int loc = idx - 1728;
    src = f1; dst = fc1t; R = 768; C = 3072; rt = loc / 96; ct = loc % 96;
  } else {
    int loc = idx - 4032;
    src = f2; dst = fc2t; R = 3072; C = 768; rt = loc / 24; ct = loc % 24;
  }
  __shared__ float tile[32][33];
  int tx = threadIdx.x & 31, ty = threadIdx.x >> 5;
  int r0 = rt * 32, c0 = ct * 32;
#pragma unroll
  for (int i = ty; i < 32; i += 8) tile[i][tx] = src[(size_t)(r0 + i) * C + c0 + tx];
  __syncthreads();
#pragma unroll
  for (int i = ty; i < 32; i += 8) dst[(size_t)(c0 + i) * R + r0 + tx] = f2b(tile[tx][i]);
}

// ========= 256x256 bf16 bt-GEMM, BK=32, 3 LDS buffers, depth-2 =========
// Tile-granularity publication: during tile t issue the 4 stage16 of tile
// t+2 (buf (t+2)%3); end of tile t: vmcnt(4) retires exactly tile t+1's
// stages (t+2's stay in flight - never drains mid-loop) + ONE barrier.
// Reads + 32 MFMA form one barrier-free region (compiler fine-grained
// lgkmcnt overlaps LDS service with MFMA). Natural layout (row stride
// 64B) is minimal-conflict for ds_read_b128 - no swizzle.
// MODE 0: +bias +pe patch scatter | 1: bf16 | 2: +bias ReLU bf16 | 4: f32
template <int MODE>
__global__ __launch_bounds__(512, 2) void gemm3b(const u16* __restrict__ A,
                                                 const u16* __restrict__ Bt,
                                                 const float* __restrict__ bias,
                                                 const float* __restrict__ pe,
                                                 float* __restrict__ Cf, u16* __restrict__ Cb,
                                                 int M, int N, int K, int lda, int nby) {
  __shared__ u16 smem[49152];  // 3 x 32 KiB tile buffers (A 8192 + B 8192 elems)
  const int tid = threadIdx.x;
  const int w = tid >> 6, l = tid & 63;
  const int lr = l & 15, lg = l >> 4;
  const int wr = w >> 2, wc = w & 3;

  // bijective XCD swizzle (m204) on flattened tile index
  const int nwg = gridDim.x;
  const int q8 = nwg >> 3, r8 = nwg & 7;
  const int xcd = blockIdx.x & 7, sidx = blockIdx.x >> 3;
  const int swz = (xcd < r8 ? xcd * (q8 + 1) : r8 * (q8 + 1) + (xcd - r8) * q8) + sidx;
  const int m0 = (swz / nby) * 256, n0 = (swz % nby) * 256;

  A += (size_t)blockIdx.z * K;
  Bt += (size_t)blockIdx.z * K;

  // staging: instr i covers rows [16i,16i+16); wave w does A{2w,2w+1}, B{2w,2w+1}
  // lane l: row +(l>>2), col (l&3)*8 -> LDS linear (row*32 + col)
  const int srow = l >> 2, scol = (l & 3) * 8;
  int raA0 = m0 + (2 * w) * 16 + srow;
  int raA1 = raA0 + 16;
  raA0 = raA0 < M ? raA0 : M - 1;
  raA1 = raA1 < M ? raA1 : M - 1;
  const int rbB0 = n0 + (2 * w) * 16 + srow;  // N multiple of 256
  const int rbB1 = rbB0 + 16;
  const u16* pA0 = A + (size_t)raA0 * lda + scol;
  const u16* pA1 = A + (size_t)raA1 * lda + scol;
  const u16* pB0 = Bt + (size_t)rbB0 * lda + scol;
  const u16* pB1 = Bt + (size_t)rbB1 * lda + scol;
  const int dsg0 = (2 * w) * 512;
  const int dsg1 = (2 * w + 1) * 512;

  // fragment read bases (elems): A row = wr*128 + m*16 + lr, B row = wc*64 + n*16 + lr
  const int aoff = (wr * 128 + lr) * 32 + lg * 8;
  const int boff = 8192 + (wc * 64 + lr) * 32 + lg * 8;

  f32x4 acc[8][4] = {};
  const int nk = K >> 5;

#define BARF                           \
  {                                    \
    __builtin_amdgcn_sched_barrier(0); \
    __builtin_amdgcn_s_barrier();      \
    asm volatile("" ::: "memory");     \
    __builtin_amdgcn_sched_barrier(0); \
  }
#define VMW(N) asm volatile("s_waitcnt vmcnt(" #N ")" ::: "memory");

  // prologue: stage tiles 0 and 1; publish tile 0
  stage16(pA0, smem + dsg0);
  stage16(pA1, smem + dsg1);
  stage16(pB0, smem + 8192 + dsg0);
  stage16(pB1, smem + 8192 + dsg1);
  stage16(pA0 + 32, smem + 16384 + dsg0);
  stage16(pA1 + 32, smem + 16384 + dsg1);
  stage16(pB0 + 32, smem + 16384 + 8192 + dsg0);
  stage16(pB1 + 32, smem + 16384 + 8192 + dsg1);
  VMW(4);  // tile 0 resident (tile 1's 4 in flight)
  BARF;

  int cur = 0;
  for (int t = 0; t < nk; ++t) {
    const u16* sb = smem + cur * 16384;
    int c2 = cur + 2;
    if (c2 >= 3) c2 -= 3;
    const bool more2 = (t + 2) < nk;
    if (more2) {
      u16* db = smem + c2 * 16384;
      const int ko = (t + 2) * 32;
      stage16(pA0 + ko, db + dsg0);
      stage16(pA1 + ko, db + dsg1);
      stage16(pB0 + ko, db + 8192 + dsg0);
      stage16(pB1 + ko, db + 8192 + dsg1);
    }
    bf16x8 ar[8], br[4];
#pragma unroll
    for (int m = 0; m < 8; ++m) ar[m] = *(const bf16x8*)(sb + aoff + m * 512);
#pragma unroll
    for (int n = 0; n < 4; ++n) br[n] = *(const bf16x8*)(sb + boff + n * 512);
    __builtin_amdgcn_s_setprio(1);
#pragma unroll
    for (int m = 0; m < 8; ++m) {
#pragma unroll
      for (int n = 0; n < 4; ++n)
        acc[m][n] = __builtin_amdgcn_mfma_f32_16x16x32_bf16(ar[m], br[n], acc[m][n], 0, 0, 0);
    }
    __builtin_amdgcn_s_setprio(0);
    if (more2) {
      VMW(4);  // retire tile t+1's stages; keep t+2's in flight
    } else if (t + 1 < nk) {
      VMW(0);  // tail: retire last tile's stages
    }
    if (t + 1 < nk) BARF;
    cur = cur == 2 ? 0 : cur + 1;
  }

  // ---- epilogue ----
  const size_t zoff = (size_t)blockIdx.z * (size_t)M * (size_t)N;
#pragma unroll
  for (int m = 0; m < 8; ++m) {
    const int rowb = m0 + wr * 128 + m * 16 + lg * 4;
#pragma unroll
    for (int n = 0; n < 4; ++n) {
      const int col = n0 + wc * 64 + n * 16 + lr;
      float bval = (MODE == 0 || MODE == 2) ? bias[col] : 0.f;
#pragma unroll
      for (int r = 0; r < 4; ++r) {
        const int row = rowb + r;
        if (row < M) {
          float v = acc[m][n][r] + bval;
          if (MODE == 2) v = fmaxf(v, 0.f);
          if (MODE == 0) {
            int b = row / NPATCH, t = 1 + row % NPATCH;
            float val = v + pe[(size_t)t * ND + col];
            size_t o = (size_t)(b * NTOK + t) * ND + col;
            Cf[o] = val;
            Cb[o] = f2b(val);
          } else if (MODE == 4) {
            Cf[zoff + (size_t)row * N + col] = v;
          } else {
            Cb[(size_t)row * N + col] = f2b(v);
          }
        }
      }
    }
  }
}

// ---------------- fused MHA: one block per (b, head) -------------------
__global__ __launch_bounds__(256) void attn_kernel(const u16* __restrict__ qkv,
                                                   float* __restrict__ att) {
  const int b = blockIdx.x, h = blockIdx.y;
  const int tid = threadIdx.x;
  const int wave = tid >> 6, lane = tid & 63;
  const int lr = lane & 15, lg = lane >> 4;
  __shared__ u16 Vt[64][232];
  __shared__ u16 Pl[4][16][232];

  const size_t bbase = (size_t)(b * NTOK) * NQKV + h * 64;

  for (int idx = tid; idx < NTOK * 64; idx += 256) {
    int k2 = idx >> 6, d = idx & 63;
    Vt[d][k2] = qkv[bbase + (size_t)k2 * NQKV + 1536 + d];
  }
  for (int idx = tid; idx < 64 * 35; idx += 256) {
    int d = idx / 35, k2 = 197 + idx % 35;
    Vt[d][k2] = 0;
  }
  for (int idx = tid; idx < 4 * 16 * 24; idx += 256) {
    int w = idx / (16 * 24), rr = (idx / 24) % 16, c = 208 + idx % 24;
    Pl[w][rr][c] = 0;
  }
  __syncthreads();

  for (int mt = wave; mt < 13; mt += 4) {
    int qrow = mt * 16 + lr;
    if (qrow > 196) qrow = 196;
    bf16x8 af[2];
#pragma unroll
    for (int ks = 0; ks < 2; ks++)
      af[ks] =
          *reinterpret_cast<const bf16x8*>(qkv + bbase + (size_t)qrow * NQKV + ks * 32 + lg * 8);

    f32x4 sf[13];
#pragma unroll
    for (int nt = 0; nt < 13; nt++) {
      int krow = nt * 16 + lr;
      if (krow > 196) krow = 196;
      f32x4 z = {0.f, 0.f, 0.f, 0.f};
#pragma unroll
      for (int ks = 0; ks < 2; ks++) {
        bf16x8 bf_ = *reinterpret_cast<const bf16x8*>(qkv + bbase + (size_t)krow * NQKV + 768 +
                                                      ks * 32 + lg * 8);
        z = __builtin_amdgcn_mfma_f32_16x16x32_bf16(af[ks], bf_, z, 0, 0, 0);
      }
      sf[nt] = z;
    }

    float sm[4];
#pragma unroll
    for (int r = 0; r < 4; r++) {
      float mx = -1e30f;
#pragma unroll
      for (int nt = 0; nt < 13; nt++) {
        int col = nt * 16 + lr;
        float val = (col < NTOK) ? sf[nt][r] * 0.125f : -1e30f;
        sf[nt][r] = val;
        mx = fmaxf(mx, val);
      }
#pragma unroll
      for (int off = 1; off < 16; off <<= 1) mx = fmaxf(mx, __shfl_xor(mx, off));
      float sum = 0.f;
#pragma unroll
      for (int nt = 0; nt < 13; nt++) {
        float pv = __expf(sf[nt][r] - mx);
        sum += pv;
        Pl[wave][lg * 4 + r][nt * 16 + lr] = f2b(pv);
      }
#pragma unroll
      for (int off = 1; off < 16; off <<= 1) sum += __shfl_xor(sum, off);
      sm[r] = sum;
    }

#pragma unroll
    for (int dt = 0; dt < 4; dt++) {
      f32x4 o = {0.f, 0.f, 0.f, 0.f};
#pragma unroll
      for (int ks = 0; ks < 7; ks++) {
        bf16x8 pa = *reinterpret_cast<const bf16x8*>(&Pl[wave][lr][ks * 32 + lg * 8]);
        bf16x8 vv = *reinterpret_cast<const bf16x8*>(&Vt[dt * 16 + lr][ks * 32 + lg * 8]);
        o = __builtin_amdgcn_mfma_f32_16x16x32_bf16(pa, vv, o, 0, 0, 0);
      }
#pragma unroll
      for (int r = 0; r < 4; r++) {
        int q = mt * 16 + lg * 4 + r;
        if (q < NTOK)
          att[(size_t)b * (NTOK * ND) + ((size_t)(h * NTOK + q)) * 64 + dt * 16 + lr] =
              o[r] / sm[r];
      }
    }
  }
}

// ---------------- LayerNorm( xa + xb ) -> f32 + bf16 -------------------
__global__ __launch_bounds__(256) void ln_kernel(const float* __restrict__ xa,
                                                 const float* __restrict__ xb,
                                                 const float* __restrict__ gw,
                                                 const float* __restrict__ bw,
                                                 float* __restrict__ yf, u16* __restrict__ yb) {
  int row = blockIdx.x, tid = threadIdx.x;
  size_t base = (size_t)row * ND;
  float v[3];
  float s = 0.f;
#pragma unroll
  for (int i = 0; i < 3; i++) {
    int d = tid + i * 256;
    v[i] = xa[base + d] + xb[base + d];
    s += v[i];
  }
  __shared__ float red[4];
  __shared__ float red2[4];
  s = wsum(s);
  if ((tid & 63) == 0) red[tid >> 6] = s;
  __syncthreads();
  float mean = (red[0] + red[1] + red[2] + red[3]) * (1.f / 768.f);
  float q = 0.f;
#pragma unroll
  for (int i = 0; i < 3; i++) {
    float d0 = v[i] - mean;
    q += d0 * d0;
  }
  q = wsum(q);
  if ((tid & 63) == 0) red2[tid >> 6] = q;
  __syncthreads();
  float inv = rsqrtf((red2[0] + red2[1] + red2[2] + red2[3]) * (1.f / 768.f) + 1e-5f);
#pragma unroll
  for (int i = 0; i < 3; i++) {
    int d = tid + i * 256;
    float val = (v[i] - mean) * inv * gw[d] + bw[d];
    yf[base + d] = val;
    yb[base + d] = f2b(val);
  }
}

// ---- LayerNorm( h1 + (p0+p1+p2) + fc2_bias ) for split-K fc2 ----------
__global__ __launch_bounds__(256) void ln_fuse2(const float* __restrict__ h1,
                                                const float* __restrict__ parts,
                                                const float* __restrict__ fb,
                                                const float* __restrict__ gw,
                                                const float* __restrict__ bw,
                                                float* __restrict__ yf, u16* __restrict__ yb) {
  const size_t PS = (size_t)NROWS * ND;
  int row = blockIdx.x, tid = threadIdx.x;
  size_t base = (size_t)row * ND;
  float v[3];
  float s = 0.f;
#pragma unroll
  for (int i = 0; i < 3; i++) {
    int d = tid + i * 256;
    v[i] = h1[base + d] + parts[base + d] + parts[PS + base + d] + parts[2 * PS + base + d] +
           fb[d];
    s += v[i];
  }
  __shared__ float red[4];
  __shared__ float red2[4];
  s = wsum(s);
  if ((tid & 63) == 0) red[tid >> 6] = s;
  __syncthreads();
  float mean = (red[0] + red[1] + red[2] + red[3]) * (1.f / 768.f);
  float q = 0.f;
#pragma unroll
  for (int i = 0; i < 3; i++) {
    float d0 = v[i] - mean;
    q += d0 * d0;
  }
  q = wsum(q);
  if ((tid & 63) == 0) red2[tid >> 6] = q;
  __syncthreads();
  float inv = rsqrtf((red2[0] + red2[1] + red2[2] + red2[3]) * (1.f / 768.f) + 1e-5f);
#pragma unroll
  for (int i = 0; i < 3; i++) {
    int d = tid + i * 256;
    float val = (v[i] - mean) * inv * gw[d] + bw[d];
    yf[base + d] = val;
    yb[base + d] = f2b(val);
  }
}

__global__ void outcopy_kernel(const float* __restrict__ h, float* __restrict__ out) {
  int idx = blockIdx.x * 256 + threadIdx.x;
  if (idx >= NB * ND) return;
  int b = idx / ND, d = idx % ND;
  out[idx] = h[(size_t)(b * NTOK) * ND + d];
}

extern "C" void kernel_launch(void* const* d_in, const int* in_sizes, int n_in, void* d_out,
                              int out_size, void* d_ws, size_t ws_size, hipStream_t stream) {
  const float* x = (const float*)d_in[0];
  const float* bng = (const float*)d_in[1];
  const float* bnb = (const float*)d_in[2];
  const float* bnm = (const float*)d_in[3];
  const float* bnv = (const float*)d_in[4];
  const float* proj_w = (const float*)d_in[5];
  const float* proj_b = (const float*)d_in[6];
  const float* cls_w = (const float*)d_in[7];
  const float* Wq = (const float*)d_in[8];
  const float* Wk = (const float*)d_in[9];
  const float* Wv = (const float*)d_in[10];
  const float* fc1_w = (const float*)d_in[11];
  const float* fc1_b = (const float*)d_in[12];
  const float* fc2_w = (const float*)d_in[13];
  const float* fc2_b = (const float*)d_in[14];
  const float* ln1_g = (const float*)d_in[15];
  const float* ln1_b = (const float*)d_in[16];
  const float* ln2_g = (const float*)d_in[17];
  const float* ln2_b = (const float*)d_in[18];

  char* wp = (char*)d_ws;
  auto carve = [&](size_t bytes) -> char* {
    char* r = wp;
    wp += (bytes + 255) & ~(size_t)255;
    return r;
  };
  float* pe = (float*)carve((size_t)NTOK * ND * 4);
  u16* patches = (u16*)carve((size_t)PROWS * ND * 2);
  u16* projwt = (u16*)carve((size_t)ND * ND * 2);
  u16* wqkvt = (u16*)carve((size_t)NQKV * ND * 2);
  u16* fc1t = (u16*)carve((size_t)ND * NDFF * 2);
  u16* fc2t = (u16*)carve((size_t)ND * NDFF * 2);
  float* h = (float*)carve((size_t)NROWS * ND * 4);
  u16* hb = (u16*)carve((size_t)NROWS * ND * 2);
  float* h1 = (float*)carve((size_t)NROWS * ND * 4);
  u16* h1b = (u16*)carve((size_t)NROWS * ND * 2);
  // union: qkvb (29 MB, dead after attn) and fc2 split-K partials (58 MB)
  char* uni = carve(3 * (size_t)NROWS * ND * 4);
  u16* qkvb = (u16*)uni;
  float* parts = (float*)uni;
  float* att = (float*)carve((size_t)NROWS * ND * 4);
  u16* ffb = (u16*)carve((size_t)NROWS * NDFF * 2);
  if ((size_t)(wp - (char*)d_ws) > ws_size) return;

  pe_kernel<<<(NTOK * ND + 255) / 256, 256, 0, stream>>>(pe);
  patch_kernel<<<(PROWS * ND + 255) / 256, 256, 0, stream>>>(x, bng, bnb, bnm, bnv, patches);
  transpose_cvt<<<dim3(24, 24), dim3(32, 8), 0, stream>>>(proj_w, projwt, ND, ND);
  gemm3b<0><<<dim3(75, 1, 1), 512, 0, stream>>>(patches, projwt, proj_b, pe, h, hb, PROWS, ND,
                                                ND, ND, 3);
  cls_kernel<<<(NB * ND + 255) / 256, 256, 0, stream>>>(cls_w, pe, h, hb);

  for (int l = 0; l < NLAY; ++l) {
    size_t wo = (size_t)l * ND * ND;
    transpose_layer<<<6336, 256, 0, stream>>>(Wq + wo, Wk + wo, Wv + wo,
                                              fc1_w + (size_t)l * ND * NDFF,
                                              fc2_w + (size_t)l * NDFF * ND, wqkvt, fc1t, fc2t);
    gemm3b<1><<<dim3(225, 1, 1), 512, 0, stream>>>(hb, wqkvt, nullptr, nullptr, nullptr, qkvb,
                                                   NROWS, NQKV, ND, ND, 9);
    attn_kernel<<<dim3(NB, NHD), 256, 0, stream>>>(qkvb, att);
    ln_kernel<<<NROWS, 256, 0, stream>>>(h, att, ln1_g + l * ND, ln1_b + l * ND, h1, h1b);
    gemm3b<2><<<dim3(300, 1, 1), 512, 0, stream>>>(h1b, fc1t, fc1_b + l * NDFF, nullptr, nullptr,
                                                   ffb, NROWS, NDFF, ND, ND, 12);
    gemm3b<4><<<dim3(75, 1, 3), 512, 0, stream>>>(ffb, fc2t, nullptr, nullptr, parts, nullptr,
                                                  NROWS, ND, 1024, NDFF, 3);
    ln_fuse2<<<NROWS, 256, 0, stream>>>(h1, parts, fc2_b + l * ND, ln2_g + l * ND, ln2_b + l * ND,
                                        h, hb);
  }
  outcopy_kernel<<<(NB * ND + 255) / 256, 256, 0, stream>>>(h, (float*)d_out);
}

// Round 7
// 2353.841 us; speedup vs baseline: 1.1521x; 1.1521x over previous
//
#include <hip/hip_runtime.h>

typedef unsigned short u16;
typedef __bf16 bf16x8 __attribute__((ext_vector_type(8)));
typedef float f32x4 __attribute__((ext_vector_type(4)));

#define NB 32
#define ND 768
#define NTOK 197
#define NROWS (NB * NTOK)   /* 6304 */
#define NPATCH 196
#define PROWS (NB * NPATCH) /* 6272 */
#define NHD 12
#define NDFF 3072
#define NLAY 12
#define NQKV 2304

// RNE float->bf16
static __device__ __forceinline__ u16 f2b(float f) {
  unsigned int u = __builtin_bit_cast(unsigned int, f);
  unsigned int r = u + 0x7FFFu + ((u >> 16) & 1u);
  return (u16)(r >> 16);
}

static __device__ __forceinline__ float wsum(float v) {
#pragma unroll
  for (int off = 32; off > 0; off >>= 1) v += __shfl_xor(v, off);
  return v;
}

static __device__ __forceinline__ void stage16(const u16* g, u16* l) {
  __builtin_amdgcn_global_load_lds((const __attribute__((address_space(1))) void*)g,
                                   (__attribute__((address_space(3))) void*)l, 16, 0, 0);
}

// ---------------- positional encoding table [197][768] ----------------
__global__ void pe_kernel(float* __restrict__ pe) {
  int idx = blockIdx.x * 256 + threadIdx.x;
  if (idx >= NTOK * ND) return;
  int t = idx / ND, d = idx % ND;
  int i = d & ~1;
  float e = (2.0f * (float)i) / (float)ND;
  float denom = powf(10000.0f, e);
  float ang = (float)t / denom;
  pe[idx] = (d & 1) ? cosf(ang) : sinf(ang);
}

// ---------------- BN + unfold-order patchify -> bf16 [6272][768] -------
__global__ void patch_kernel(const float* __restrict__ x,
                             const float* __restrict__ bng, const float* __restrict__ bnb,
                             const float* __restrict__ bnm, const float* __restrict__ bnv,
                             u16* __restrict__ out) {
  int idx = blockIdx.x * 256 + threadIdx.x;
  if (idx >= PROWS * ND) return;
  int row = idx / ND, col = idx % ND;
  int b = row / NPATCH, s = row % NPATCH;
  int ph = s / 14, pw = s % 14;
  int c = col / 256, rr = col % 256;
  int py = rr / 16, px = rr % 16;
  float v = x[(((size_t)(b * 3 + c) * 224) + ph * 16 + py) * 224 + pw * 16 + px];
  v = (v - bnm[c]) * rsqrtf(bnv[c] + 1e-5f) * bng[c] + bnb[c];
  out[idx] = f2b(v);
}

// ---------------- cls token row (t=0) + pe[0] --------------------------
__global__ void cls_kernel(const float* __restrict__ cls_w, const float* __restrict__ pe,
                           float* __restrict__ h, u16* __restrict__ hb) {
  int idx = blockIdx.x * 256 + threadIdx.x;
  if (idx >= NB * ND) return;
  int b = idx / ND, d = idx % ND;
  float v = cls_w[d] + pe[d];
  size_t o = (size_t)(b * NTOK) * ND + d;
  h[o] = v;
  hb[o] = f2b(v);
}

// ---------------- fp32 [R][C] -> bf16 [C][R] transpose-convert ---------
__global__ __launch_bounds__(256) void transpose_cvt(const float* __restrict__ src,
                                                     u16* __restrict__ dst, int R, int C) {
  __shared__ float tile[32][33];
  int tx = threadIdx.x, ty = threadIdx.y;
  int c0 = blockIdx.x * 32, r0 = blockIdx.y * 32;
#pragma unroll
  for (int i = ty; i < 32; i += 8) {
    int r = r0 + i, c = c0 + tx;
    tile[i][tx] = (r < R && c < C) ? src[(size_t)r * C + c] : 0.f;
  }
  __syncthreads();
#pragma unroll
  for (int i = ty; i < 32; i += 8) {
    int c = c0 + i, r = r0 + tx;
    if (r < R && c < C) dst[(size_t)c * R + r] = f2b(tile[tx][i]);
  }
}

// -------- all 5 weight transposes of one layer in a single launch ------
__global__ __launch_bounds__(256) void transpose_layer(
    const float* __restrict__ Wq, const float* __restrict__ Wk, const float* __restrict__ Wv,
    const float* __restrict__ f1, const float* __restrict__ f2,
    u16* __restrict__ wqkvt, u16* __restrict__ fc1t, u16* __restrict__ fc2t) {
  int idx = blockIdx.x;
  const float* src;
  u16* dst;
  int C, R, rt, ct;
  if (idx < 1728) {
    int z = idx / 576, loc = idx % 576;
    src = z == 0 ? Wq : (z == 1 ? Wk : Wv);
    dst = wqkvt + (size_t)z * ND * ND;
    R = 768; C = 768; rt = loc / 24; ct = loc % 24;
  } else if (idx < 4032) {
    int loc = idx - 1728;
    src = f1; dst = fc1t; R = 768; C = 3072; rt = loc / 96; ct = loc % 96;
  } else {
    int loc = idx - 4032;
    src = f2; dst = fc2t; R = 3072; C = 768; rt = loc / 24; ct = loc % 24;
  }
  __shared__ float tile[32][33];
  int tx = threadIdx.x & 31, ty = threadIdx.x >> 5;
  int r0 = rt * 32, c0 = ct * 32;
#pragma unroll
  for (int i = ty; i < 32; i += 8) tile[i][tx] = src[(size_t)(r0 + i) * C + c0 + tx];
  __syncthreads();
#pragma unroll
  for (int i = ty; i < 32; i += 8) dst[(size_t)(c0 + i) * R + r0 + tx] = f2b(tile[tx][i]);
}

// ======== 256x128 bf16 bt-GEMM, BK=32, 3 LDS bufs, 2 blocks/CU =========
// R6's proven depth-2 counted pipeline, resized for occupancy-2:
// 72 KiB LDS (3 x 24 KiB), acc[4][4] (64 VGPR), __launch_bounds__(512,4)
// -> 4 waves/SIMD -> 2 blocks/CU -> inter-block overlap hides barrier
// and LDS-burst stalls (m114 mechanism). 2-way-free XOR swizzle for
// 64B rows: col-slot ^= (row&3)^((row>>2)&3), inverse applied on the
// global source (lane-uniform: slot(l) = (l&3)^((l>>2)&3)^((l>>4)&3)),
// forward on ds_read -> every 16-lane phase hits each bank-quad 2x.
// MODE 0: +bias +pe patch scatter | 1: bf16 | 2: +bias ReLU bf16 | 4: f32
template <int MODE>
__global__ __launch_bounds__(512, 4) void gemm2(const u16* __restrict__ A,
                                                const u16* __restrict__ Bt,
                                                const float* __restrict__ bias,
                                                const float* __restrict__ pe,
                                                float* __restrict__ Cf, u16* __restrict__ Cb,
                                                int M, int N, int K, int lda, int nby) {
  __shared__ u16 smem[36864];  // 3 x 12288 elems (A 8192 + B 4096)
  const int tid = threadIdx.x;
  const int w = tid >> 6, l = tid & 63;
  const int lr = l & 15, lg = l >> 4;
  const int wr = w >> 1, wc = w & 1;

  // bijective XCD swizzle (m204) on flattened tile index
  const int nwg = gridDim.x;
  const int q8 = nwg >> 3, r8 = nwg & 7;
  const int xcd = blockIdx.x & 7, sidx = blockIdx.x >> 3;
  const int swz = (xcd < r8 ? xcd * (q8 + 1) : r8 * (q8 + 1) + (xcd - r8) * q8) + sidx;
  const int m0 = (swz / nby) * 256, n0 = (swz % nby) * 128;

  A += (size_t)blockIdx.z * K;
  Bt += (size_t)blockIdx.z * K;

  // staging: 16-row segments of 512 elems; wave w: A segs {2w,2w+1}, B seg {w}
  const int srow = l >> 2;
  const int scol = (((l & 3) ^ ((l >> 2) & 3) ^ ((l >> 4) & 3))) * 8;  // inv-swizzled source
  int raA0 = m0 + 32 * w + srow;
  int raA1 = raA0 + 16;
  raA0 = raA0 < M ? raA0 : M - 1;
  raA1 = raA1 < M ? raA1 : M - 1;
  const int rbB = n0 + 16 * w + srow;  // N multiple of 128
  const u16* pA0 = A + (size_t)raA0 * lda + scol;
  const u16* pA1 = A + (size_t)raA1 * lda + scol;
  const u16* pB = Bt + (size_t)rbB * lda + scol;
  const int dsgA0 = (2 * w) * 512;
  const int dsgA1 = (2 * w + 1) * 512;
  const int dsgB = 8192 + w * 512;

  // fragment reads (swizzled): A row = wr*64 + m*16 + lr, B row = wc*64 + n*16 + lr
  const int xo = ((lg ^ (lr & 3) ^ ((lr >> 2) & 3))) * 8;
  const int aoff = (wr * 64 + lr) * 32 + xo;
  const int boff = 8192 + (wc * 64 + lr) * 32 + xo;

  f32x4 acc[4][4] = {};
  const int nk = K >> 5;

#define BARF                           \
  {                                    \
    __builtin_amdgcn_sched_barrier(0); \
    __builtin_amdgcn_s_barrier();      \
    asm volatile("" ::: "memory");     \
    __builtin_amdgcn_sched_barrier(0); \
  }
#define VMW(N) asm volatile("s_waitcnt vmcnt(" #N ")" ::: "memory");

  // prologue: stage tiles 0 and 1; publish tile 0
  stage16(pA0, smem + dsgA0);
  stage16(pA1, smem + dsgA1);
  stage16(pB, smem + dsgB);
  stage16(pA0 + 32, smem + 12288 + dsgA0);
  stage16(pA1 + 32, smem + 12288 + dsgA1);
  stage16(pB + 32, smem + 12288 + dsgB);
  VMW(3);  // tile 0 resident (tile 1's 3 in flight)
  BARF;

  int cur = 0;
  for (int t = 0; t < nk; ++t) {
    const u16* sb = smem + cur * 12288;
    int c2 = cur + 2;
    if (c2 >= 3) c2 -= 3;
    const bool more2 = (t + 2) < nk;
    if (more2) {
      u16* db = smem + c2 * 12288;
      const int ko = (t + 2) * 32;
      stage16(pA0 + ko, db + dsgA0);
      stage16(pA1 + ko, db + dsgA1);
      stage16(pB + ko, db + dsgB);
    }
    bf16x8 ar[4], br[4];
#pragma unroll
    for (int n = 0; n < 4; ++n) br[n] = *(const bf16x8*)(sb + boff + n * 512);
#pragma unroll
    for (int m = 0; m < 4; ++m) ar[m] = *(const bf16x8*)(sb + aoff + m * 512);
    __builtin_amdgcn_s_setprio(1);
#pragma unroll
    for (int m = 0; m < 4; ++m) {
#pragma unroll
      for (int n = 0; n < 4; ++n)
        acc[m][n] = __builtin_amdgcn_mfma_f32_16x16x32_bf16(ar[m], br[n], acc[m][n], 0, 0, 0);
    }
    __builtin_amdgcn_s_setprio(0);
    if (more2) {
      VMW(3);  // retire tile t+1's stages; keep t+2's in flight
    } else if (t + 1 < nk) {
      VMW(0);  // tail: retire last tile's stages
    }
    if (t + 1 < nk) BARF;
    cur = cur == 2 ? 0 : cur + 1;
  }

  // ---- epilogue ----
  const size_t zoff = (size_t)blockIdx.z * (size_t)M * (size_t)N;
#pragma unroll
  for (int m = 0; m < 4; ++m) {
    const int rowb = m0 + wr * 64 + m * 16 + lg * 4;
#pragma unroll
    for (int n = 0; n < 4; ++n) {
      const int col = n0 + wc * 64 + n * 16 + lr;
      float bval = (MODE == 0 || MODE == 2) ? bias[col] : 0.f;
#pragma unroll
      for (int r = 0; r < 4; ++r) {
        const int row = rowb + r;
        if (row < M) {
          float v = acc[m][n][r] + bval;
          if (MODE == 2) v = fmaxf(v, 0.f);
          if (MODE == 0) {
            int b = row / NPATCH, t = 1 + row % NPATCH;
            float val = v + pe[(size_t)t * ND + col];
            size_t o = (size_t)(b * NTOK + t) * ND + col;
            Cf[o] = val;
            Cb[o] = f2b(val);
          } else if (MODE == 4) {
            Cf[zoff + (size_t)row * N + col] = v;
          } else {
            Cb[(size_t)row * N + col] = f2b(v);
          }
        }
      }
    }
  }
}

// ---------------- fused MHA: one block per (b, head) -------------------
__global__ __launch_bounds__(256) void attn_kernel(const u16* __restrict__ qkv,
                                                   float* __restrict__ att) {
  const int b = blockIdx.x, h = blockIdx.y;
  const int tid = threadIdx.x;
  const int wave = tid >> 6, lane = tid & 63;
  const int lr = lane & 15, lg = lane >> 4;
  __shared__ u16 Vt[64][232];
  __shared__ u16 Pl[4][16][232];

  const size_t bbase = (size_t)(b * NTOK) * NQKV + h * 64;

  for (int idx = tid; idx < NTOK * 64; idx += 256) {
    int k2 = idx >> 6, d = idx & 63;
    Vt[d][k2] = qkv[bbase + (size_t)k2 * NQKV + 1536 + d];
  }
  for (int idx = tid; idx < 64 * 35; idx += 256) {
    int d = idx / 35, k2 = 197 + idx % 35;
    Vt[d][k2] = 0;
  }
  for (int idx = tid; idx < 4 * 16 * 24; idx += 256) {
    int w = idx / (16 * 24), rr = (idx / 24) % 16, c = 208 + idx % 24;
    Pl[w][rr][c] = 0;
  }
  __syncthreads();

  for (int mt = wave; mt < 13; mt += 4) {
    int qrow = mt * 16 + lr;
    if (qrow > 196) qrow = 196;
    bf16x8 af[2];
#pragma unroll
    for (int ks = 0; ks < 2; ks++)
      af[ks] =
          *reinterpret_cast<const bf16x8*>(qkv + bbase + (size_t)qrow * NQKV + ks * 32 + lg * 8);

    f32x4 sf[13];
#pragma unroll
    for (int nt = 0; nt < 13; nt++) {
      int krow = nt * 16 + lr;
      if (krow > 196) krow = 196;
      f32x4 z = {0.f, 0.f, 0.f, 0.f};
#pragma unroll
      for (int ks = 0; ks < 2; ks++) {
        bf16x8 bf_ = *reinterpret_cast<const bf16x8*>(qkv + bbase + (size_t)krow * NQKV + 768 +
                                                      ks * 32 + lg * 8);
        z = __builtin_amdgcn_mfma_f32_16x16x32_bf16(af[ks], bf_, z, 0, 0, 0);
      }
      sf[nt] = z;
    }

    float sm[4];
#pragma unroll
    for (int r = 0; r < 4; r++) {
      float mx = -1e30f;
#pragma unroll
      for (int nt = 0; nt < 13; nt++) {
        int col = nt * 16 + lr;
        float val = (col < NTOK) ? sf[nt][r] * 0.125f : -1e30f;
        sf[nt][r] = val;
        mx = fmaxf(mx, val);
      }
#pragma unroll
      for (int off = 1; off < 16; off <<= 1) mx = fmaxf(mx, __shfl_xor(mx, off));
      float sum = 0.f;
#pragma unroll
      for (int nt = 0; nt < 13; nt++) {
        float pv = __expf(sf[nt][r] - mx);
        sum += pv;
        Pl[wave][lg * 4 + r][nt * 16 + lr] = f2b(pv);
      }
#pragma unroll
      for (int off = 1; off < 16; off <<= 1) sum += __shfl_xor(sum, off);
      sm[r] = sum;
    }

#pragma unroll
    for (int dt = 0; dt < 4; dt++) {
      f32x4 o = {0.f, 0.f, 0.f, 0.f};
#pragma unroll
      for (int ks = 0; ks < 7; ks++) {
        bf16x8 pa = *reinterpret_cast<const bf16x8*>(&Pl[wave][lr][ks * 32 + lg * 8]);
        bf16x8 vv = *reinterpret_cast<const bf16x8*>(&Vt[dt * 16 + lr][ks * 32 + lg * 8]);
        o = __builtin_amdgcn_mfma_f32_16x16x32_bf16(pa, vv, o, 0, 0, 0);
      }
#pragma unroll
      for (int r = 0; r < 4; r++) {
        int q = mt * 16 + lg * 4 + r;
        if (q < NTOK)
          att[(size_t)b * (NTOK * ND) + ((size_t)(h * NTOK + q)) * 64 + dt * 16 + lr] =
              o[r] / sm[r];
      }
    }
  }
}

// ---------------- LayerNorm( xa + xb ) -> f32 + bf16 -------------------
__global__ __launch_bounds__(256) void ln_kernel(const float* __restrict__ xa,
                                                 const float* __restrict__ xb,
                                                 const float* __restrict__ gw,
                                                 const float* __restrict__ bw,
                                                 float* __restrict__ yf, u16* __restrict__ yb) {
  int row = blockIdx.x, tid = threadIdx.x;
  size_t base = (size_t)row * ND;
  float v[3];
  float s = 0.f;
#pragma unroll
  for (int i = 0; i < 3; i++) {
    int d = tid + i * 256;
    v[i] = xa[base + d] + xb[base + d];
    s += v[i];
  }
  __shared__ float red[4];
  __shared__ float red2[4];
  s = wsum(s);
  if ((tid & 63) == 0) red[tid >> 6] = s;
  __syncthreads();
  float mean = (red[0] + red[1] + red[2] + red[3]) * (1.f / 768.f);
  float q = 0.f;
#pragma unroll
  for (int i = 0; i < 3; i++) {
    float d0 = v[i] - mean;
    q += d0 * d0;
  }
  q = wsum(q);
  if ((tid & 63) == 0) red2[tid >> 6] = q;
  __syncthreads();
  float inv = rsqrtf((red2[0] + red2[1] + red2[2] + red2[3]) * (1.f / 768.f) + 1e-5f);
#pragma unroll
  for (int i = 0; i < 3; i++) {
    int d = tid + i * 256;
    float val = (v[i] - mean) * inv * gw[d] + bw[d];
    yf[base + d] = val;
    yb[base + d] = f2b(val);
  }
}

// ---- LayerNorm( h1 + (p0+p1+p2) + fc2_bias ) for split-K fc2 ----------
__global__ __launch_bounds__(256) void ln_fuse2(const float* __restrict__ h1,
                                                const float* __restrict__ parts,
                                                const float* __restrict__ fb,
                                                const float* __restrict__ gw,
                                                const float* __restrict__ bw,
                                                float* __restrict__ yf, u16* __restrict__ yb) {
  const size_t PS = (size_t)NROWS * ND;
  int row = blockIdx.x, tid = threadIdx.x;
  size_t base = (size_t)row * ND;
  float v[3];
  float s = 0.f;
#pragma unroll
  for (int i = 0; i < 3; i++) {
    int d = tid + i * 256;
    v[i] = h1[base + d] + parts[base + d] + parts[PS + base + d] + parts[2 * PS + base + d] +
           fb[d];
    s += v[i];
  }
  __shared__ float red[4];
  __shared__ float red2[4];
  s = wsum(s);
  if ((tid & 63) == 0) red[tid >> 6] = s;
  __syncthreads();
  float mean = (red[0] + red[1] + red[2] + red[3]) * (1.f / 768.f);
  float q = 0.f;
#pragma unroll
  for (int i = 0; i < 3; i++) {
    float d0 = v[i] - mean;
    q += d0 * d0;
  }
  q = wsum(q);
  if ((tid & 63) == 0) red2[tid >> 6] = q;
  __syncthreads();
  float inv = rsqrtf((red2[0] + red2[1] + red2[2] + red2[3]) * (1.f / 768.f) + 1e-5f);
#pragma unroll
  for (int i = 0; i < 3; i++) {
    int d = tid + i * 256;
    float val = (v[i] - mean) * inv * gw[d] + bw[d];
    yf[base + d] = val;
    yb[base + d] = f2b(val);
  }
}

__global__ void outcopy_kernel(const float* __restrict__ h, float* __restrict__ out) {
  int idx = blockIdx.x * 256 + threadIdx.x;
  if (idx >= NB * ND) return;
  int b = idx / ND, d = idx % ND;
  out[idx] = h[(size_t)(b * NTOK) * ND + d];
}

extern "C" void kernel_launch(void* const* d_in, const int* in_sizes, int n_in, void* d_out,
                              int out_size, void* d_ws, size_t ws_size, hipStream_t stream) {
  const float* x = (const float*)d_in[0];
  const float* bng = (const float*)d_in[1];
  const float* bnb = (const float*)d_in[2];
  const float* bnm = (const float*)d_in[3];
  const float* bnv = (const float*)d_in[4];
  const float* proj_w = (const float*)d_in[5];
  const float* proj_b = (const float*)d_in[6];
  const float* cls_w = (const float*)d_in[7];
  const float* Wq = (const float*)d_in[8];
  const float* Wk = (const float*)d_in[9];
  const float* Wv = (const float*)d_in[10];
  const float* fc1_w = (const float*)d_in[11];
  const float* fc1_b = (const float*)d_in[12];
  const float* fc2_w = (const float*)d_in[13];
  const float* fc2_b = (const float*)d_in[14];
  const float* ln1_g = (const float*)d_in[15];
  const float* ln1_b = (const float*)d_in[16];
  const float* ln2_g = (const float*)d_in[17];
  const float* ln2_b = (const float*)d_in[18];

  char* wp = (char*)d_ws;
  auto carve = [&](size_t bytes) -> char* {
    char* r = wp;
    wp += (bytes + 255) & ~(size_t)255;
    return r;
  };
  float* pe = (float*)carve((size_t)NTOK * ND * 4);
  u16* patches = (u16*)carve((size_t)PROWS * ND * 2);
  u16* projwt = (u16*)carve((size_t)ND * ND * 2);
  u16* wqkvt = (u16*)carve((size_t)NQKV * ND * 2);
  u16* fc1t = (u16*)carve((size_t)ND * NDFF * 2);
  u16* fc2t = (u16*)carve((size_t)ND * NDFF * 2);
  float* h = (float*)carve((size_t)NROWS * ND * 4);
  u16* hb = (u16*)carve((size_t)NROWS * ND * 2);
  float* h1 = (float*)carve((size_t)NROWS * ND * 4);
  u16* h1b = (u16*)carve((size_t)NROWS * ND * 2);
  // union: qkvb (29 MB, dead after attn) and fc2 split-K partials (58 MB)
  char* uni = carve(3 * (size_t)NROWS * ND * 4);
  u16* qkvb = (u16*)uni;
  float* parts = (float*)uni;
  float* att = (float*)carve((size_t)NROWS * ND * 4);
  u16* ffb = (u16*)carve((size_t)NROWS * NDFF * 2);
  if ((size_t)(wp - (char*)d_ws) > ws_size) return;

  pe_kernel<<<(NTOK * ND + 255) / 256, 256, 0, stream>>>(pe);
  patch_kernel<<<(PROWS * ND + 255) / 256, 256, 0, stream>>>(x, bng, bnb, bnm, bnv, patches);
  transpose_cvt<<<dim3(24, 24), dim3(32, 8), 0, stream>>>(proj_w, projwt, ND, ND);
  gemm2<0><<<dim3(150, 1, 1), 512, 0, stream>>>(patches, projwt, proj_b, pe, h, hb, PROWS, ND,
                                                ND, ND, 6);
  cls_kernel<<<(NB * ND + 255) / 256, 256, 0, stream>>>(cls_w, pe, h, hb);

  for (int l = 0; l < NLAY; ++l) {
    size_t wo = (size_t)l * ND * ND;
    transpose_layer<<<6336, 256, 0, stream>>>(Wq + wo, Wk + wo, Wv + wo,
                                              fc1_w + (size_t)l * ND * NDFF,
                                              fc2_w + (size_t)l * NDFF * ND, wqkvt, fc1t, fc2t);
    gemm2<1><<<dim3(450, 1, 1), 512, 0, stream>>>(hb, wqkvt, nullptr, nullptr, nullptr, qkvb,
                                                  NROWS, NQKV, ND, ND, 18);
    attn_kernel<<<dim3(NB, NHD), 256, 0, stream>>>(qkvb, att);
    ln_kernel<<<NROWS, 256, 0, stream>>>(h, att, ln1_g + l * ND, ln1_b + l * ND, h1, h1b);
    gemm2<2><<<dim3(600, 1, 1), 512, 0, stream>>>(h1b, fc1t, fc1_b + l * NDFF, nullptr, nullptr,
                                                  ffb, NROWS, NDFF, ND, ND, 24);
    gemm2<4><<<dim3(150, 1, 3), 512, 0, stream>>>(ffb, fc2t, nullptr, nullptr, parts, nullptr,
                                                  NROWS, ND, 1024, NDFF, 6);
    ln_fuse2<<<NROWS, 256, 0, stream>>>(h1, parts, fc2_b + l * ND, ln2_g + l * ND, ln2_b + l * ND,
                                        h, hb);
  }
  outcopy_kernel<<<(NB * ND + 255) / 256, 256, 0, stream>>>(h, (float*)d_out);
}

// Round 8
// 2268.116 us; speedup vs baseline: 1.1956x; 1.0378x over previous
//
#include <hip/hip_runtime.h>

typedef unsigned short u16;
typedef unsigned int u32;
typedef __bf16 bf16x8 __attribute__((ext_vector_type(8)));
typedef float f32x4 __attribute__((ext_vector_type(4)));
typedef u16 u16x8 __attribute__((ext_vector_type(8)));

#define NB 32
#define ND 768
#define NTOK 197
#define NROWS (NB * NTOK)   /* 6304 */
#define NPATCH 196
#define PROWS (NB * NPATCH) /* 6272 */
#define NHD 12
#define NDFF 3072
#define NLAY 12
#define NQKV 2304

// RNE float->bf16
static __device__ __forceinline__ u16 f2b(float f) {
  u32 u = __builtin_bit_cast(u32, f);
  u32 r = u + 0x7FFFu + ((u >> 16) & 1u);
  return (u16)(r >> 16);
}
static __device__ __forceinline__ float b2f(u16 u) {
  u32 x = ((u32)u) << 16;
  return __builtin_bit_cast(float, x);
}

static __device__ __forceinline__ float wsum(float v) {
#pragma unroll
  for (int off = 32; off > 0; off >>= 1) v += __shfl_xor(v, off);
  return v;
}

static __device__ __forceinline__ void stage16(const u16* g, u16* l) {
  __builtin_amdgcn_global_load_lds((const __attribute__((address_space(1))) void*)g,
                                   (__attribute__((address_space(3))) void*)l, 16, 0, 0);
}

// ---------------- positional encoding table [197][768] ----------------
__global__ void pe_kernel(float* __restrict__ pe) {
  int idx = blockIdx.x * 256 + threadIdx.x;
  if (idx >= NTOK * ND) return;
  int t = idx / ND, d = idx % ND;
  int i = d & ~1;
  float e = (2.0f * (float)i) / (float)ND;
  float denom = powf(10000.0f, e);
  float ang = (float)t / denom;
  pe[idx] = (d & 1) ? cosf(ang) : sinf(ang);
}

// ------- BN + unfold-order patchify -> bf16 [6272][768], 8 px/thread ---
__global__ void patch_kernel(const float* __restrict__ x,
                             const float* __restrict__ bng, const float* __restrict__ bnb,
                             const float* __restrict__ bnm, const float* __restrict__ bnv,
                             u16* __restrict__ out) {
  int idx = blockIdx.x * 256 + threadIdx.x;
  if (idx >= PROWS * 96) return;
  int row = idx / 96, c8 = (idx % 96) * 8;
  int b = row / NPATCH, s = row % NPATCH;
  int ph = s / 14, pw = s % 14;
  int c = c8 / 256, rr = c8 % 256;
  int py = rr / 16, px0 = rr % 16;  // 0 or 8
  const float* xp =
      x + (((size_t)(b * 3 + c) * 224) + ph * 16 + py) * 224 + pw * 16 + px0;
  float scale = rsqrtf(bnv[c] + 1e-5f) * bng[c];
  float sub = bnm[c], add = bnb[c];
  u16x8 o;
#pragma unroll
  for (int j = 0; j < 8; j++) o[j] = f2b((xp[j] - sub) * scale + add);
  *reinterpret_cast<u16x8*>(out + (size_t)idx * 8) = o;
}

// ---------------- cls token row (t=0) + pe[0] --------------------------
__global__ void cls_kernel(const float* __restrict__ cls_w, const float* __restrict__ pe,
                           float* __restrict__ h, u16* __restrict__ hb) {
  int idx = blockIdx.x * 256 + threadIdx.x;
  if (idx >= NB * ND) return;
  int b = idx / ND, d = idx % ND;
  float v = cls_w[d] + pe[d];
  size_t o = (size_t)(b * NTOK) * ND + d;
  h[o] = v;
  hb[o] = f2b(v);
}

// ---------------- fp32 [R][C] -> bf16 [C][R] transpose-convert ---------
__global__ __launch_bounds__(256) void transpose_cvt(const float* __restrict__ src,
                                                     u16* __restrict__ dst, int R, int C) {
  __shared__ float tile[32][33];
  int tx = threadIdx.x, ty = threadIdx.y;
  int c0 = blockIdx.x * 32, r0 = blockIdx.y * 32;
#pragma unroll
  for (int i = ty; i < 32; i += 8) {
    int r = r0 + i, c = c0 + tx;
    tile[i][tx] = (r < R && c < C) ? src[(size_t)r * C + c] : 0.f;
  }
  __syncthreads();
#pragma unroll
  for (int i = ty; i < 32; i += 8) {
    int c = c0 + i, r = r0 + tx;
    if (r < R && c < C) dst[(size_t)c * R + r] = f2b(tile[tx][i]);
  }
}

// ---- all 5 weight transposes of one layer: 64x64 tiles, 512 thr -------
// grid 1584: [0,432) qkv 12x12x3; [432,1008) fc1 12x48; [1008,1584) fc2 48x12
__global__ __launch_bounds__(512) void transpose_layer(
    const float* __restrict__ Wq, const float* __restrict__ Wk, const float* __restrict__ Wv,
    const float* __restrict__ f1, const float* __restrict__ f2,
    u16* __restrict__ wqkvt, u16* __restrict__ fc1t, u16* __restrict__ fc2t) {
  int idx = blockIdx.x;
  const float* src;
  u16* dst;
  int C, R, rt, ct;
  if (idx < 432) {
    int z = idx / 144, loc = idx % 144;
    src = z == 0 ? Wq : (z == 1 ? Wk : Wv);
    dst = wqkvt + (size_t)z * ND * ND;
    R = 768; C = 768; rt = loc / 12; ct = loc % 12;
  } else if (idx < 1008) {
    int loc = idx - 432;
    src = f1; dst = fc1t; R = 768; C = 3072; rt = loc / 48; ct = loc % 48;
  } else {
    int loc = idx - 1008;
    src = f2; dst = fc2t; R = 3072; C = 768; rt = loc / 12; ct = loc % 12;
  }
  __shared__ float tile[64][65];
  const int l2 = threadIdx.x & 31, rp = threadIdx.x >> 5;  // 0..15
  const int r0 = rt * 64, c0 = ct * 64;
#pragma unroll
  for (int i = rp; i < 64; i += 16) {
    float2 v = *reinterpret_cast<const float2*>(src + (size_t)(r0 + i) * C + c0 + l2 * 2);
    tile[i][l2 * 2] = v.x;
    tile[i][l2 * 2 + 1] = v.y;
  }
  __syncthreads();
#pragma unroll
  for (int j = rp; j < 64; j += 16) {
    u32 o = (u32)f2b(tile[l2 * 2][j]) | ((u32)f2b(tile[l2 * 2 + 1][j]) << 16);
    *reinterpret_cast<u32*>(dst + (size_t)(c0 + j) * R + r0 + l2 * 2) = o;
  }
}

// ======== 256x128 bf16 bt-GEMM, BK=32, 3 LDS bufs, 2 blocks/CU =========
// (unchanged from round 7 except MODE 4 now writes bf16 partials)
// MODE 0: +bias +pe patch scatter | 1: bf16 | 2: +bias ReLU bf16
// MODE 4: bf16 out at z-offset (split-K partials)
template <int MODE>
__global__ __launch_bounds__(512, 4) void gemm2(const u16* __restrict__ A,
                                                const u16* __restrict__ Bt,
                                                const float* __restrict__ bias,
                                                const float* __restrict__ pe,
                                                float* __restrict__ Cf, u16* __restrict__ Cb,
                                                int M, int N, int K, int lda, int nby) {
  __shared__ u16 smem[36864];  // 3 x 12288 elems (A 8192 + B 4096)
  const int tid = threadIdx.x;
  const int w = tid >> 6, l = tid & 63;
  const int lr = l & 15, lg = l >> 4;
  const int wr = w >> 1, wc = w & 1;

  const int nwg = gridDim.x;
  const int q8 = nwg >> 3, r8 = nwg & 7;
  const int xcd = blockIdx.x & 7, sidx = blockIdx.x >> 3;
  const int swz = (xcd < r8 ? xcd * (q8 + 1) : r8 * (q8 + 1) + (xcd - r8) * q8) + sidx;
  const int m0 = (swz / nby) * 256, n0 = (swz % nby) * 128;

  A += (size_t)blockIdx.z * K;
  Bt += (size_t)blockIdx.z * K;

  const int srow = l >> 2;
  const int scol = (((l & 3) ^ ((l >> 2) & 3) ^ ((l >> 4) & 3))) * 8;
  int raA0 = m0 + 32 * w + srow;
  int raA1 = raA0 + 16;
  raA0 = raA0 < M ? raA0 : M - 1;
  raA1 = raA1 < M ? raA1 : M - 1;
  const int rbB = n0 + 16 * w + srow;
  const u16* pA0 = A + (size_t)raA0 * lda + scol;
  const u16* pA1 = A + (size_t)raA1 * lda + scol;
  const u16* pB = Bt + (size_t)rbB * lda + scol;
  const int dsgA0 = (2 * w) * 512;
  const int dsgA1 = (2 * w + 1) * 512;
  const int dsgB = 8192 + w * 512;

  const int xo = ((lg ^ (lr & 3) ^ ((lr >> 2) & 3))) * 8;
  const int aoff = (wr * 64 + lr) * 32 + xo;
  const int boff = 8192 + (wc * 64 + lr) * 32 + xo;

  f32x4 acc[4][4] = {};
  const int nk = K >> 5;

#define BARF                           \
  {                                    \
    __builtin_amdgcn_sched_barrier(0); \
    __builtin_amdgcn_s_barrier();      \
    asm volatile("" ::: "memory");     \
    __builtin_amdgcn_sched_barrier(0); \
  }
#define VMW(N) asm volatile("s_waitcnt vmcnt(" #N ")" ::: "memory");

  stage16(pA0, smem + dsgA0);
  stage16(pA1, smem + dsgA1);
  stage16(pB, smem + dsgB);
  stage16(pA0 + 32, smem + 12288 + dsgA0);
  stage16(pA1 + 32, smem + 12288 + dsgA1);
  stage16(pB + 32, smem + 12288 + dsgB);
  VMW(3);
  BARF;

  int cur = 0;
  for (int t = 0; t < nk; ++t) {
    const u16* sb = smem + cur * 12288;
    int c2 = cur + 2;
    if (c2 >= 3) c2 -= 3;
    const bool more2 = (t + 2) < nk;
    if (more2) {
      u16* db = smem + c2 * 12288;
      const int ko = (t + 2) * 32;
      stage16(pA0 + ko, db + dsgA0);
      stage16(pA1 + ko, db + dsgA1);
      stage16(pB + ko, db + dsgB);
    }
    bf16x8 ar[4], br[4];
#pragma unroll
    for (int n = 0; n < 4; ++n) br[n] = *(const bf16x8*)(sb + boff + n * 512);
#pragma unroll
    for (int m = 0; m < 4; ++m) ar[m] = *(const bf16x8*)(sb + aoff + m * 512);
    __builtin_amdgcn_s_setprio(1);
#pragma unroll
    for (int m = 0; m < 4; ++m) {
#pragma unroll
      for (int n = 0; n < 4; ++n)
        acc[m][n] = __builtin_amdgcn_mfma_f32_16x16x32_bf16(ar[m], br[n], acc[m][n], 0, 0, 0);
    }
    __builtin_amdgcn_s_setprio(0);
    if (more2) {
      VMW(3);
    } else if (t + 1 < nk) {
      VMW(0);
    }
    if (t + 1 < nk) BARF;
    cur = cur == 2 ? 0 : cur + 1;
  }

  // ---- epilogue ----
  const size_t zoff = (size_t)blockIdx.z * (size_t)M * (size_t)N;
#pragma unroll
  for (int m = 0; m < 4; ++m) {
    const int rowb = m0 + wr * 64 + m * 16 + lg * 4;
#pragma unroll
    for (int n = 0; n < 4; ++n) {
      const int col = n0 + wc * 64 + n * 16 + lr;
      float bval = (MODE == 0 || MODE == 2) ? bias[col] : 0.f;
#pragma unroll
      for (int r = 0; r < 4; ++r) {
        const int row = rowb + r;
        if (row < M) {
          float v = acc[m][n][r] + bval;
          if (MODE == 2) v = fmaxf(v, 0.f);
          if (MODE == 0) {
            int b = row / NPATCH, t = 1 + row % NPATCH;
            float val = v + pe[(size_t)t * ND + col];
            size_t o = (size_t)(b * NTOK + t) * ND + col;
            Cf[o] = val;
            Cb[o] = f2b(val);
          } else if (MODE == 4) {
            Cb[zoff + (size_t)row * N + col] = f2b(v);
          } else {
            Cb[(size_t)row * N + col] = f2b(v);
          }
        }
      }
    }
  }
}

// ---------------- fused MHA: one block per (b, head), bf16 out ---------
__global__ __launch_bounds__(256) void attn_kernel(const u16* __restrict__ qkv,
                                                   u16* __restrict__ att) {
  const int b = blockIdx.x, h = blockIdx.y;
  const int tid = threadIdx.x;
  const int wave = tid >> 6, lane = tid & 63;
  const int lr = lane & 15, lg = lane >> 4;
  __shared__ u16 Vt[64][232];
  __shared__ u16 Pl[4][16][232];

  const size_t bbase = (size_t)(b * NTOK) * NQKV + h * 64;

  for (int idx = tid; idx < NTOK * 64; idx += 256) {
    int k2 = idx >> 6, d = idx & 63;
    Vt[d][k2] = qkv[bbase + (size_t)k2 * NQKV + 1536 + d];
  }
  for (int idx = tid; idx < 64 * 35; idx += 256) {
    int d = idx / 35, k2 = 197 + idx % 35;
    Vt[d][k2] = 0;
  }
  for (int idx = tid; idx < 4 * 16 * 24; idx += 256) {
    int w = idx / (16 * 24), rr = (idx / 24) % 16, c = 208 + idx % 24;
    Pl[w][rr][c] = 0;
  }
  __syncthreads();

  for (int mt = wave; mt < 13; mt += 4) {
    int qrow = mt * 16 + lr;
    if (qrow > 196) qrow = 196;
    bf16x8 af[2];
#pragma unroll
    for (int ks = 0; ks < 2; ks++)
      af[ks] =
          *reinterpret_cast<const bf16x8*>(qkv + bbase + (size_t)qrow * NQKV + ks * 32 + lg * 8);

    f32x4 sf[13];
#pragma unroll
    for (int nt = 0; nt < 13; nt++) {
      int krow = nt * 16 + lr;
      if (krow > 196) krow = 196;
      f32x4 z = {0.f, 0.f, 0.f, 0.f};
#pragma unroll
      for (int ks = 0; ks < 2; ks++) {
        bf16x8 bf_ = *reinterpret_cast<const bf16x8*>(qkv + bbase + (size_t)krow * NQKV + 768 +
                                                      ks * 32 + lg * 8);
        z = __builtin_amdgcn_mfma_f32_16x16x32_bf16(af[ks], bf_, z, 0, 0, 0);
      }
      sf[nt] = z;
    }

    float sm[4];
#pragma unroll
    for (int r = 0; r < 4; r++) {
      float mx = -1e30f;
#pragma unroll
      for (int nt = 0; nt < 13; nt++) {
        int col = nt * 16 + lr;
        float val = (col < NTOK) ? sf[nt][r] * 0.125f : -1e30f;
        sf[nt][r] = val;
        mx = fmaxf(mx, val);
      }
#pragma unroll
      for (int off = 1; off < 16; off <<= 1) mx = fmaxf(mx, __shfl_xor(mx, off));
      float sum = 0.f;
#pragma unroll
      for (int nt = 0; nt < 13; nt++) {
        float pv = __expf(sf[nt][r] - mx);
        sum += pv;
        Pl[wave][lg * 4 + r][nt * 16 + lr] = f2b(pv);
      }
#pragma unroll
      for (int off = 1; off < 16; off <<= 1) sum += __shfl_xor(sum, off);
      sm[r] = sum;
    }

#pragma unroll
    for (int dt = 0; dt < 4; dt++) {
      f32x4 o = {0.f, 0.f, 0.f, 0.f};
#pragma unroll
      for (int ks = 0; ks < 7; ks++) {
        bf16x8 pa = *reinterpret_cast<const bf16x8*>(&Pl[wave][lr][ks * 32 + lg * 8]);
        bf16x8 vv = *reinterpret_cast<const bf16x8*>(&Vt[dt * 16 + lr][ks * 32 + lg * 8]);
        o = __builtin_amdgcn_mfma_f32_16x16x32_bf16(pa, vv, o, 0, 0, 0);
      }
#pragma unroll
      for (int r = 0; r < 4; r++) {
        int q = mt * 16 + lg * 4 + r;
        if (q < NTOK)
          att[(size_t)b * (NTOK * ND) + ((size_t)(h * NTOK + q)) * 64 + dt * 16 + lr] =
              f2b(o[r] / sm[r]);
      }
    }
  }
}

// ------- LayerNorm( xa_f32 + xb_bf16 ) -> f32 + bf16, 384 thr, 8B/lane -
__global__ __launch_bounds__(384) void ln_kernel(const float* __restrict__ xa,
                                                 const u16* __restrict__ xb,
                                                 const float* __restrict__ gw,
                                                 const float* __restrict__ bw,
                                                 float* __restrict__ yf, u16* __restrict__ yb) {
  int row = blockIdx.x, tid = threadIdx.x;
  size_t p2 = (size_t)row * 384 + tid;  // float2 / u32 index
  float2 a = reinterpret_cast<const float2*>(xa)[p2];
  u32 bb = reinterpret_cast<const u32*>(xb)[p2];
  float v0 = a.x + b2f((u16)(bb & 0xffff));
  float v1 = a.y + b2f((u16)(bb >> 16));
  __shared__ float red[8], red2[8];
  float s = wsum(v0 + v1);
  if ((tid & 63) == 0) red[tid >> 6] = s;
  __syncthreads();
  float mean = (red[0] + red[1] + red[2] + red[3] + red[4] + red[5]) * (1.f / 768.f);
  float d0 = v0 - mean, d1 = v1 - mean;
  float q = wsum(d0 * d0 + d1 * d1);
  if ((tid & 63) == 0) red2[tid >> 6] = q;
  __syncthreads();
  float inv =
      rsqrtf((red2[0] + red2[1] + red2[2] + red2[3] + red2[4] + red2[5]) * (1.f / 768.f) + 1e-5f);
  int d = tid * 2;
  float o0 = d0 * inv * gw[d] + bw[d];
  float o1 = d1 * inv * gw[d + 1] + bw[d + 1];
  float2 of = {o0, o1};
  reinterpret_cast<float2*>(yf)[p2] = of;
  reinterpret_cast<u32*>(yb)[p2] = (u32)f2b(o0) | ((u32)f2b(o1) << 16);
}

// -- LayerNorm( h1 + sum3(bf16 parts) + fc2_bias ), 384 thr, 8B/lane ----
__global__ __launch_bounds__(384) void ln_fuse2(const float* __restrict__ h1,
                                                const u16* __restrict__ parts,
                                                const float* __restrict__ fb,
                                                const float* __restrict__ gw,
                                                const float* __restrict__ bw,
                                                float* __restrict__ yf, u16* __restrict__ yb) {
  const size_t PS2 = (size_t)NROWS * ND / 2;  // u32 units per part
  int row = blockIdx.x, tid = threadIdx.x;
  size_t p2 = (size_t)row * 384 + tid;
  float2 a = reinterpret_cast<const float2*>(h1)[p2];
  const u32* pp = reinterpret_cast<const u32*>(parts);
  u32 q0 = pp[p2], q1 = pp[PS2 + p2], q2 = pp[2 * PS2 + p2];
  int d = tid * 2;
  float v0 = a.x + b2f((u16)(q0 & 0xffff)) + b2f((u16)(q1 & 0xffff)) + b2f((u16)(q2 & 0xffff)) +
             fb[d];
  float v1 = a.y + b2f((u16)(q0 >> 16)) + b2f((u16)(q1 >> 16)) + b2f((u16)(q2 >> 16)) + fb[d + 1];
  __shared__ float red[8], red2[8];
  float s = wsum(v0 + v1);
  if ((tid & 63) == 0) red[tid >> 6] = s;
  __syncthreads();
  float mean = (red[0] + red[1] + red[2] + red[3] + red[4] + red[5]) * (1.f / 768.f);
  float d0 = v0 - mean, d1 = v1 - mean;
  float q = wsum(d0 * d0 + d1 * d1);
  if ((tid & 63) == 0) red2[tid >> 6] = q;
  __syncthreads();
  float inv =
      rsqrtf((red2[0] + red2[1] + red2[2] + red2[3] + red2[4] + red2[5]) * (1.f / 768.f) + 1e-5f);
  float o0 = d0 * inv * gw[d] + bw[d];
  float o1 = d1 * inv * gw[d + 1] + bw[d + 1];
  float2 of = {o0, o1};
  reinterpret_cast<float2*>(yf)[p2] = of;
  reinterpret_cast<u32*>(yb)[p2] = (u32)f2b(o0) | ((u32)f2b(o1) << 16);
}

__global__ void outcopy_kernel(const float* __restrict__ h, float* __restrict__ out) {
  int idx = blockIdx.x * 256 + threadIdx.x;
  if (idx >= NB * ND) return;
  int b = idx / ND, d = idx % ND;
  out[idx] = h[(size_t)(b * NTOK) * ND + d];
}

extern "C" void kernel_launch(void* const* d_in, const int* in_sizes, int n_in, void* d_out,
                              int out_size, void* d_ws, size_t ws_size, hipStream_t stream) {
  const float* x = (const float*)d_in[0];
  const float* bng = (const float*)d_in[1];
  const float* bnb = (const float*)d_in[2];
  const float* bnm = (const float*)d_in[3];
  const float* bnv = (const float*)d_in[4];
  const float* proj_w = (const float*)d_in[5];
  const float* proj_b = (const float*)d_in[6];
  const float* cls_w = (const float*)d_in[7];
  const float* Wq = (const float*)d_in[8];
  const float* Wk = (const float*)d_in[9];
  const float* Wv = (const float*)d_in[10];
  const float* fc1_w = (const float*)d_in[11];
  const float* fc1_b = (const float*)d_in[12];
  const float* fc2_w = (const float*)d_in[13];
  const float* fc2_b = (const float*)d_in[14];
  const float* ln1_g = (const float*)d_in[15];
  const float* ln1_b = (const float*)d_in[16];
  const float* ln2_g = (const float*)d_in[17];
  const float* ln2_b = (const float*)d_in[18];

  char* wp = (char*)d_ws;
  auto carve = [&](size_t bytes) -> char* {
    char* r = wp;
    wp += (bytes + 255) & ~(size_t)255;
    return r;
  };
  float* pe = (float*)carve((size_t)NTOK * ND * 4);
  u16* patches = (u16*)carve((size_t)PROWS * ND * 2);
  u16* projwt = (u16*)carve((size_t)ND * ND * 2);
  u16* wqkvt = (u16*)carve((size_t)NQKV * ND * 2);
  u16* fc1t = (u16*)carve((size_t)ND * NDFF * 2);
  u16* fc2t = (u16*)carve((size_t)ND * NDFF * 2);
  float* h = (float*)carve((size_t)NROWS * ND * 4);
  u16* hb = (u16*)carve((size_t)NROWS * ND * 2);
  float* h1 = (float*)carve((size_t)NROWS * ND * 4);
  u16* h1b = (u16*)carve((size_t)NROWS * ND * 2);
  // union: qkvb (29 MB, dead after attn) and fc2 bf16 split-K partials (29 MB)
  char* uni = carve(3 * (size_t)NROWS * ND * 2);
  u16* qkvb = (u16*)uni;
  u16* parts = (u16*)uni;
  u16* att = (u16*)carve((size_t)NROWS * ND * 2);
  u16* ffb = (u16*)carve((size_t)NROWS * NDFF * 2);
  if ((size_t)(wp - (char*)d_ws) > ws_size) return;

  pe_kernel<<<(NTOK * ND + 255) / 256, 256, 0, stream>>>(pe);
  patch_kernel<<<(PROWS * 96 + 255) / 256, 256, 0, stream>>>(x, bng, bnb, bnm, bnv, patches);
  transpose_cvt<<<dim3(24, 24), dim3(32, 8), 0, stream>>>(proj_w, projwt, ND, ND);
  gemm2<0><<<dim3(150, 1, 1), 512, 0, stream>>>(patches, projwt, proj_b, pe, h, hb, PROWS, ND,
                                                ND, ND, 6);
  cls_kernel<<<(NB * ND + 255) / 256, 256, 0, stream>>>(cls_w, pe, h, hb);

  for (int l = 0; l < NLAY; ++l) {
    size_t wo = (size_t)l * ND * ND;
    transpose_layer<<<1584, 512, 0, stream>>>(Wq + wo, Wk + wo, Wv + wo,
                                              fc1_w + (size_t)l * ND * NDFF,
                                              fc2_w + (size_t)l * NDFF * ND, wqkvt, fc1t, fc2t);
    gemm2<1><<<dim3(450, 1, 1), 512, 0, stream>>>(hb, wqkvt, nullptr, nullptr, nullptr, qkvb,
                                                  NROWS, NQKV, ND, ND, 18);
    attn_kernel<<<dim3(NB, NHD), 256, 0, stream>>>(qkvb, att);
    ln_kernel<<<NROWS, 384, 0, stream>>>(h, att, ln1_g + l * ND, ln1_b + l * ND, h1, h1b);
    gemm2<2><<<dim3(600, 1, 1), 512, 0, stream>>>(h1b, fc1t, fc1_b + l * NDFF, nullptr, nullptr,
                                                  ffb, NROWS, NDFF, ND, ND, 24);
    gemm2<4><<<dim3(150, 1, 3), 512, 0, stream>>>(ffb, fc2t, nullptr, nullptr, nullptr, parts,
                                                  NROWS, ND, 1024, NDFF, 6);
    ln_fuse2<<<NROWS, 384, 0, stream>>>(h1, parts, fc2_b + l * ND, ln2_g + l * ND, ln2_b + l * ND,
                                        h, hb);
  }
  outcopy_kernel<<<(NB * ND + 255) / 256, 256, 0, stream>>>(h, (float*)d_out);
}

// Round 9
// 2218.460 us; speedup vs baseline: 1.2224x; 1.0224x over previous
//
#include <hip/hip_runtime.h>

typedef unsigned short u16;
typedef unsigned int u32;
typedef __bf16 bf16x8 __attribute__((ext_vector_type(8)));
typedef float f32x4 __attribute__((ext_vector_type(4)));
typedef u16 u16x8 __attribute__((ext_vector_type(8)));

#define NB 32
#define ND 768
#define NTOK 197
#define NROWS (NB * NTOK)   /* 6304 */
#define NPATCH 196
#define PROWS (NB * NPATCH) /* 6272 */
#define NHD 12
#define NDFF 3072
#define NLAY 12
#define NQKV 2304

// RNE float->bf16
static __device__ __forceinline__ u16 f2b(float f) {
  u32 u = __builtin_bit_cast(u32, f);
  u32 r = u + 0x7FFFu + ((u >> 16) & 1u);
  return (u16)(r >> 16);
}
static __device__ __forceinline__ float b2f(u16 u) {
  u32 x = ((u32)u) << 16;
  return __builtin_bit_cast(float, x);
}

static __device__ __forceinline__ float wsum(float v) {
#pragma unroll
  for (int off = 32; off > 0; off >>= 1) v += __shfl_xor(v, off);
  return v;
}

static __device__ __forceinline__ void stage16(const u16* g, u16* l) {
  __builtin_amdgcn_global_load_lds((const __attribute__((address_space(1))) void*)g,
                                   (__attribute__((address_space(3))) void*)l, 16, 0, 0);
}

// ---------------- positional encoding table [197][768] ----------------
__global__ void pe_kernel(float* __restrict__ pe) {
  int idx = blockIdx.x * 256 + threadIdx.x;
  if (idx >= NTOK * ND) return;
  int t = idx / ND, d = idx % ND;
  int i = d & ~1;
  float e = (2.0f * (float)i) / (float)ND;
  float denom = powf(10000.0f, e);
  float ang = (float)t / denom;
  pe[idx] = (d & 1) ? cosf(ang) : sinf(ang);
}

// ------- BN + unfold-order patchify -> bf16 [6272][768], 8 px/thread ---
__global__ void patch_kernel(const float* __restrict__ x,
                             const float* __restrict__ bng, const float* __restrict__ bnb,
                             const float* __restrict__ bnm, const float* __restrict__ bnv,
                             u16* __restrict__ out) {
  int idx = blockIdx.x * 256 + threadIdx.x;
  if (idx >= PROWS * 96) return;
  int row = idx / 96, c8 = (idx % 96) * 8;
  int b = row / NPATCH, s = row % NPATCH;
  int ph = s / 14, pw = s % 14;
  int c = c8 / 256, rr = c8 % 256;
  int py = rr / 16, px0 = rr % 16;  // 0 or 8
  const float* xp =
      x + (((size_t)(b * 3 + c) * 224) + ph * 16 + py) * 224 + pw * 16 + px0;
  float scale = rsqrtf(bnv[c] + 1e-5f) * bng[c];
  float sub = bnm[c], add = bnb[c];
  u16x8 o;
#pragma unroll
  for (int j = 0; j < 8; j++) o[j] = f2b((xp[j] - sub) * scale + add);
  *reinterpret_cast<u16x8*>(out + (size_t)idx * 8) = o;
}

// ---------------- cls token row (t=0) + pe[0], bf16 trunk --------------
__global__ void cls_kernel(const float* __restrict__ cls_w, const float* __restrict__ pe,
                           u16* __restrict__ hb) {
  int idx = blockIdx.x * 256 + threadIdx.x;
  if (idx >= NB * ND) return;
  int b = idx / ND, d = idx % ND;
  hb[(size_t)(b * NTOK) * ND + d] = f2b(cls_w[d] + pe[d]);
}

// ---------------- fp32 [R][C] -> bf16 [C][R] transpose-convert ---------
__global__ __launch_bounds__(256) void transpose_cvt(const float* __restrict__ src,
                                                     u16* __restrict__ dst, int R, int C) {
  __shared__ float tile[32][33];
  int tx = threadIdx.x, ty = threadIdx.y;
  int c0 = blockIdx.x * 32, r0 = blockIdx.y * 32;
#pragma unroll
  for (int i = ty; i < 32; i += 8) {
    int r = r0 + i, c = c0 + tx;
    tile[i][tx] = (r < R && c < C) ? src[(size_t)r * C + c] : 0.f;
  }
  __syncthreads();
#pragma unroll
  for (int i = ty; i < 32; i += 8) {
    int c = c0 + i, r = r0 + tx;
    if (r < R && c < C) dst[(size_t)c * R + r] = f2b(tile[tx][i]);
  }
}

// ---- all 5 weight transposes of one layer: 64x64 tiles, 512 thr -------
__global__ __launch_bounds__(512) void transpose_layer(
    const float* __restrict__ Wq, const float* __restrict__ Wk, const float* __restrict__ Wv,
    const float* __restrict__ f1, const float* __restrict__ f2,
    u16* __restrict__ wqkvt, u16* __restrict__ fc1t, u16* __restrict__ fc2t) {
  int idx = blockIdx.x;
  const float* src;
  u16* dst;
  int C, R, rt, ct;
  if (idx < 432) {
    int z = idx / 144, loc = idx % 144;
    src = z == 0 ? Wq : (z == 1 ? Wk : Wv);
    dst = wqkvt + (size_t)z * ND * ND;
    R = 768; C = 768; rt = loc / 12; ct = loc % 12;
  } else if (idx < 1008) {
    int loc = idx - 432;
    src = f1; dst = fc1t; R = 768; C = 3072; rt = loc / 48; ct = loc % 48;
  } else {
    int loc = idx - 1008;
    src = f2; dst = fc2t; R = 3072; C = 768; rt = loc / 12; ct = loc % 12;
  }
  __shared__ float tile[64][65];
  const int l2 = threadIdx.x & 31, rp = threadIdx.x >> 5;  // 0..15
  const int r0 = rt * 64, c0 = ct * 64;
#pragma unroll
  for (int i = rp; i < 64; i += 16) {
    float2 v = *reinterpret_cast<const float2*>(src + (size_t)(r0 + i) * C + c0 + l2 * 2);
    tile[i][l2 * 2] = v.x;
    tile[i][l2 * 2 + 1] = v.y;
  }
  __syncthreads();
#pragma unroll
  for (int j = rp; j < 64; j += 16) {
    u32 o = (u32)f2b(tile[l2 * 2][j]) | ((u32)f2b(tile[l2 * 2 + 1][j]) << 16);
    *reinterpret_cast<u32*>(dst + (size_t)(c0 + j) * R + r0 + l2 * 2) = o;
  }
}

// ======== 256x128 bf16 bt-GEMM, BK=32, 3 LDS bufs, 2 blocks/CU =========
// MODE 0: +bias +pe patch scatter (bf16) | 1: bf16 | 2: +bias ReLU bf16
// MODE 4: bf16 out at z-offset (split-K partials)
template <int MODE>
__global__ __launch_bounds__(512, 4) void gemm2(const u16* __restrict__ A,
                                                const u16* __restrict__ Bt,
                                                const float* __restrict__ bias,
                                                const float* __restrict__ pe,
                                                u16* __restrict__ Cb,
                                                int M, int N, int K, int lda, int nby) {
  __shared__ u16 smem[36864];  // 3 x 12288 elems (A 8192 + B 4096)
  const int tid = threadIdx.x;
  const int w = tid >> 6, l = tid & 63;
  const int lr = l & 15, lg = l >> 4;
  const int wr = w >> 1, wc = w & 1;

  const int nwg = gridDim.x;
  const int q8 = nwg >> 3, r8 = nwg & 7;
  const int xcd = blockIdx.x & 7, sidx = blockIdx.x >> 3;
  const int swz = (xcd < r8 ? xcd * (q8 + 1) : r8 * (q8 + 1) + (xcd - r8) * q8) + sidx;
  const int m0 = (swz / nby) * 256, n0 = (swz % nby) * 128;

  A += (size_t)blockIdx.z * K;
  Bt += (size_t)blockIdx.z * K;

  const int srow = l >> 2;
  const int scol = (((l & 3) ^ ((l >> 2) & 3) ^ ((l >> 4) & 3))) * 8;
  int raA0 = m0 + 32 * w + srow;
  int raA1 = raA0 + 16;
  raA0 = raA0 < M ? raA0 : M - 1;
  raA1 = raA1 < M ? raA1 : M - 1;
  const int rbB = n0 + 16 * w + srow;
  const u16* pA0 = A + (size_t)raA0 * lda + scol;
  const u16* pA1 = A + (size_t)raA1 * lda + scol;
  const u16* pB = Bt + (size_t)rbB * lda + scol;
  const int dsgA0 = (2 * w) * 512;
  const int dsgA1 = (2 * w + 1) * 512;
  const int dsgB = 8192 + w * 512;

  const int xo = ((lg ^ (lr & 3) ^ ((lr >> 2) & 3))) * 8;
  const int aoff = (wr * 64 + lr) * 32 + xo;
  const int boff = 8192 + (wc * 64 + lr) * 32 + xo;

  f32x4 acc[4][4] = {};
  const int nk = K >> 5;

#define BARF                           \
  {                                    \
    __builtin_amdgcn_sched_barrier(0); \
    __builtin_amdgcn_s_barrier();      \
    asm volatile("" ::: "memory");     \
    __builtin_amdgcn_sched_barrier(0); \
  }
#define VMW(N) asm volatile("s_waitcnt vmcnt(" #N ")" ::: "memory");

  stage16(pA0, smem + dsgA0);
  stage16(pA1, smem + dsgA1);
  stage16(pB, smem + dsgB);
  stage16(pA0 + 32, smem + 12288 + dsgA0);
  stage16(pA1 + 32, smem + 12288 + dsgA1);
  stage16(pB + 32, smem + 12288 + dsgB);
  VMW(3);
  BARF;

  int cur = 0;
  for (int t = 0; t < nk; ++t) {
    const u16* sb = smem + cur * 12288;
    int c2 = cur + 2;
    if (c2 >= 3) c2 -= 3;
    const bool more2 = (t + 2) < nk;
    if (more2) {
      u16* db = smem + c2 * 12288;
      const int ko = (t + 2) * 32;
      stage16(pA0 + ko, db + dsgA0);
      stage16(pA1 + ko, db + dsgA1);
      stage16(pB + ko, db + dsgB);
    }
    bf16x8 ar[4], br[4];
#pragma unroll
    for (int n = 0; n < 4; ++n) br[n] = *(const bf16x8*)(sb + boff + n * 512);
#pragma unroll
    for (int m = 0; m < 4; ++m) ar[m] = *(const bf16x8*)(sb + aoff + m * 512);
    __builtin_amdgcn_s_setprio(1);
#pragma unroll
    for (int m = 0; m < 4; ++m) {
#pragma unroll
      for (int n = 0; n < 4; ++n)
        acc[m][n] = __builtin_amdgcn_mfma_f32_16x16x32_bf16(ar[m], br[n], acc[m][n], 0, 0, 0);
    }
    __builtin_amdgcn_s_setprio(0);
    if (more2) {
      VMW(3);
    } else if (t + 1 < nk) {
      VMW(0);
    }
    if (t + 1 < nk) BARF;
    cur = cur == 2 ? 0 : cur + 1;
  }

  // ---- epilogue ----
  const size_t zoff = (size_t)blockIdx.z * (size_t)M * (size_t)N;
#pragma unroll
  for (int m = 0; m < 4; ++m) {
    const int rowb = m0 + wr * 64 + m * 16 + lg * 4;
#pragma unroll
    for (int n = 0; n < 4; ++n) {
      const int col = n0 + wc * 64 + n * 16 + lr;
      float bval = (MODE == 0 || MODE == 2) ? bias[col] : 0.f;
#pragma unroll
      for (int r = 0; r < 4; ++r) {
        const int row = rowb + r;
        if (row < M) {
          float v = acc[m][n][r] + bval;
          if (MODE == 2) v = fmaxf(v, 0.f);
          if (MODE == 0) {
            int b = row / NPATCH, t = 1 + row % NPATCH;
            float val = v + pe[(size_t)t * ND + col];
            Cb[(size_t)(b * NTOK + t) * ND + col] = f2b(val);
          } else if (MODE == 4) {
            Cb[zoff + (size_t)row * N + col] = f2b(v);
          } else {
            Cb[(size_t)row * N + col] = f2b(v);
          }
        }
      }
    }
  }
}

// ---------------- fused MHA: one block per (b, head), bf16 out ---------
__global__ __launch_bounds__(256) void attn_kernel(const u16* __restrict__ qkv,
                                                   u16* __restrict__ att) {
  const int b = blockIdx.x, h = blockIdx.y;
  const int tid = threadIdx.x;
  const int wave = tid >> 6, lane = tid & 63;
  const int lr = lane & 15, lg = lane >> 4;
  __shared__ u16 Vt[64][232];
  __shared__ u16 Pl[4][16][232];

  const size_t bbase = (size_t)(b * NTOK) * NQKV + h * 64;

  // stage V^T: vectorized 16B global reads, scalar LDS scatter
  for (int idx = tid; idx < NTOK * 8; idx += 256) {
    int k2 = idx >> 3, d0 = (idx & 7) * 8;
    u16x8 v = *reinterpret_cast<const u16x8*>(qkv + bbase + (size_t)k2 * NQKV + 1536 + d0);
#pragma unroll
    for (int j = 0; j < 8; j++) Vt[d0 + j][k2] = v[j];
  }
  for (int idx = tid; idx < 64 * 35; idx += 256) {
    int d = idx / 35, k2 = 197 + idx % 35;
    Vt[d][k2] = 0;
  }
  for (int idx = tid; idx < 4 * 16 * 24; idx += 256) {
    int w = idx / (16 * 24), rr = (idx / 24) % 16, c = 208 + idx % 24;
    Pl[w][rr][c] = 0;
  }
  __syncthreads();

  for (int mt = wave; mt < 13; mt += 4) {
    int qrow = mt * 16 + lr;
    if (qrow > 196) qrow = 196;
    bf16x8 af[2];
#pragma unroll
    for (int ks = 0; ks < 2; ks++)
      af[ks] =
          *reinterpret_cast<const bf16x8*>(qkv + bbase + (size_t)qrow * NQKV + ks * 32 + lg * 8);

    f32x4 sf[13];
#pragma unroll
    for (int nt = 0; nt < 13; nt++) {
      int krow = nt * 16 + lr;
      if (krow > 196) krow = 196;
      f32x4 z = {0.f, 0.f, 0.f, 0.f};
#pragma unroll
      for (int ks = 0; ks < 2; ks++) {
        bf16x8 bf_ = *reinterpret_cast<const bf16x8*>(qkv + bbase + (size_t)krow * NQKV + 768 +
                                                      ks * 32 + lg * 8);
        z = __builtin_amdgcn_mfma_f32_16x16x32_bf16(af[ks], bf_, z, 0, 0, 0);
      }
      sf[nt] = z;
    }

    float sm[4];
#pragma unroll
    for (int r = 0; r < 4; r++) {
      float mx = -1e30f;
#pragma unroll
      for (int nt = 0; nt < 13; nt++) {
        int col = nt * 16 + lr;
        float val = (col < NTOK) ? sf[nt][r] * 0.125f : -1e30f;
        sf[nt][r] = val;
        mx = fmaxf(mx, val);
      }
#pragma unroll
      for (int off = 1; off < 16; off <<= 1) mx = fmaxf(mx, __shfl_xor(mx, off));
      float sum = 0.f;
#pragma unroll
      for (int nt = 0; nt < 13; nt++) {
        float pv = __expf(sf[nt][r] - mx);
        sum += pv;
        Pl[wave][lg * 4 + r][nt * 16 + lr] = f2b(pv);
      }
#pragma unroll
      for (int off = 1; off < 16; off <<= 1) sum += __shfl_xor(sum, off);
      sm[r] = sum;
    }

#pragma unroll
    for (int dt = 0; dt < 4; dt++) {
      f32x4 o = {0.f, 0.f, 0.f, 0.f};
#pragma unroll
      for (int ks = 0; ks < 7; ks++) {
        bf16x8 pa = *reinterpret_cast<const bf16x8*>(&Pl[wave][lr][ks * 32 + lg * 8]);
        bf16x8 vv = *reinterpret_cast<const bf16x8*>(&Vt[dt * 16 + lr][ks * 32 + lg * 8]);
        o = __builtin_amdgcn_mfma_f32_16x16x32_bf16(pa, vv, o, 0, 0, 0);
      }
#pragma unroll
      for (int r = 0; r < 4; r++) {
        int q = mt * 16 + lg * 4 + r;
        if (q < NTOK)
          att[(size_t)b * (NTOK * ND) + ((size_t)(h * NTOK + q)) * 64 + dt * 16 + lr] =
              f2b(o[r] / sm[r]);
      }
    }
  }
}

// ---- LayerNorm( trunk_bf16 + att_bf16 ) -> bf16, 384 thr, 4B/lane -----
__global__ __launch_bounds__(384) void ln_kernel(const u16* __restrict__ xa,
                                                 const u16* __restrict__ xb,
                                                 const float* __restrict__ gw,
                                                 const float* __restrict__ bw,
                                                 u16* __restrict__ yb) {
  int row = blockIdx.x, tid = threadIdx.x;
  size_t p2 = (size_t)row * 384 + tid;  // u32 index
  u32 aa = reinterpret_cast<const u32*>(xa)[p2];
  u32 bb = reinterpret_cast<const u32*>(xb)[p2];
  float v0 = b2f((u16)(aa & 0xffff)) + b2f((u16)(bb & 0xffff));
  float v1 = b2f((u16)(aa >> 16)) + b2f((u16)(bb >> 16));
  __shared__ float red[8], red2[8];
  float s = wsum(v0 + v1);
  if ((tid & 63) == 0) red[tid >> 6] = s;
  __syncthreads();
  float mean = (red[0] + red[1] + red[2] + red[3] + red[4] + red[5]) * (1.f / 768.f);
  float d0 = v0 - mean, d1 = v1 - mean;
  float q = wsum(d0 * d0 + d1 * d1);
  if ((tid & 63) == 0) red2[tid >> 6] = q;
  __syncthreads();
  float inv =
      rsqrtf((red2[0] + red2[1] + red2[2] + red2[3] + red2[4] + red2[5]) * (1.f / 768.f) + 1e-5f);
  int d = tid * 2;
  float o0 = d0 * inv * gw[d] + bw[d];
  float o1 = d1 * inv * gw[d + 1] + bw[d + 1];
  reinterpret_cast<u32*>(yb)[p2] = (u32)f2b(o0) | ((u32)f2b(o1) << 16);
}

// -- LayerNorm( h1b + sum3(bf16 parts) + fc2_bias ) -> bf16 trunk -------
__global__ __launch_bounds__(384) void ln_fuse2(const u16* __restrict__ h1b,
                                                const u16* __restrict__ parts,
                                                const float* __restrict__ fb,
                                                const float* __restrict__ gw,
                                                const float* __restrict__ bw,
                                                u16* __restrict__ yb) {
  const size_t PS2 = (size_t)NROWS * ND / 2;  // u32 units per part
  int row = blockIdx.x, tid = threadIdx.x;
  size_t p2 = (size_t)row * 384 + tid;
  u32 aa = reinterpret_cast<const u32*>(h1b)[p2];
  const u32* pp = reinterpret_cast<const u32*>(parts);
  u32 q0 = pp[p2], q1 = pp[PS2 + p2], q2 = pp[2 * PS2 + p2];
  int d = tid * 2;
  float v0 = b2f((u16)(aa & 0xffff)) + b2f((u16)(q0 & 0xffff)) + b2f((u16)(q1 & 0xffff)) +
             b2f((u16)(q2 & 0xffff)) + fb[d];
  float v1 = b2f((u16)(aa >> 16)) + b2f((u16)(q0 >> 16)) + b2f((u16)(q1 >> 16)) +
             b2f((u16)(q2 >> 16)) + fb[d + 1];
  __shared__ float red[8], red2[8];
  float s = wsum(v0 + v1);
  if ((tid & 63) == 0) red[tid >> 6] = s;
  __syncthreads();
  float mean = (red[0] + red[1] + red[2] + red[3] + red[4] + red[5]) * (1.f / 768.f);
  float d0 = v0 - mean, d1 = v1 - mean;
  float q = wsum(d0 * d0 + d1 * d1);
  if ((tid & 63) == 0) red2[tid >> 6] = q;
  __syncthreads();
  float inv =
      rsqrtf((red2[0] + red2[1] + red2[2] + red2[3] + red2[4] + red2[5]) * (1.f / 768.f) + 1e-5f);
  float o0 = d0 * inv * gw[d] + bw[d];
  float o1 = d1 * inv * gw[d + 1] + bw[d + 1];
  reinterpret_cast<u32*>(yb)[p2] = (u32)f2b(o0) | ((u32)f2b(o1) << 16);
}

__global__ void outcopy_kernel(const u16* __restrict__ hb, float* __restrict__ out) {
  int idx = blockIdx.x * 256 + threadIdx.x;
  if (idx >= NB * ND) return;
  int b = idx / ND, d = idx % ND;
  out[idx] = b2f(hb[(size_t)(b * NTOK) * ND + d]);
}

extern "C" void kernel_launch(void* const* d_in, const int* in_sizes, int n_in, void* d_out,
                              int out_size, void* d_ws, size_t ws_size, hipStream_t stream) {
  const float* x = (const float*)d_in[0];
  const float* bng = (const float*)d_in[1];
  const float* bnb = (const float*)d_in[2];
  const float* bnm = (const float*)d_in[3];
  const float* bnv = (const float*)d_in[4];
  const float* proj_w = (const float*)d_in[5];
  const float* proj_b = (const float*)d_in[6];
  const float* cls_w = (const float*)d_in[7];
  const float* Wq = (const float*)d_in[8];
  const float* Wk = (const float*)d_in[9];
  const float* Wv = (const float*)d_in[10];
  const float* fc1_w = (const float*)d_in[11];
  const float* fc1_b = (const float*)d_in[12];
  const float* fc2_w = (const float*)d_in[13];
  const float* fc2_b = (const float*)d_in[14];
  const float* ln1_g = (const float*)d_in[15];
  const float* ln1_b = (const float*)d_in[16];
  const float* ln2_g = (const float*)d_in[17];
  const float* ln2_b = (const float*)d_in[18];

  char* wp = (char*)d_ws;
  auto carve = [&](size_t bytes) -> char* {
    char* r = wp;
    wp += (bytes + 255) & ~(size_t)255;
    return r;
  };
  float* pe = (float*)carve((size_t)NTOK * ND * 4);
  u16* patches = (u16*)carve((size_t)PROWS * ND * 2);
  u16* projwt = (u16*)carve((size_t)ND * ND * 2);
  u16* wqkvt = (u16*)carve((size_t)NQKV * ND * 2);
  u16* fc1t = (u16*)carve((size_t)ND * NDFF * 2);
  u16* fc2t = (u16*)carve((size_t)ND * NDFF * 2);
  u16* hb = (u16*)carve((size_t)NROWS * ND * 2);
  u16* h1b = (u16*)carve((size_t)NROWS * ND * 2);
  // union: qkvb (29 MB, dead after attn) and fc2 bf16 split-K partials (29 MB)
  char* uni = carve(3 * (size_t)NROWS * ND * 2);
  u16* qkvb = (u16*)uni;
  u16* parts = (u16*)uni;
  u16* att = (u16*)carve((size_t)NROWS * ND * 2);
  u16* ffb = (u16*)carve((size_t)NROWS * NDFF * 2);
  if ((size_t)(wp - (char*)d_ws) > ws_size) return;

  pe_kernel<<<(NTOK * ND + 255) / 256, 256, 0, stream>>>(pe);
  patch_kernel<<<(PROWS * 96 + 255) / 256, 256, 0, stream>>>(x, bng, bnb, bnm, bnv, patches);
  transpose_cvt<<<dim3(24, 24), dim3(32, 8), 0, stream>>>(proj_w, projwt, ND, ND);
  gemm2<0><<<dim3(150, 1, 1), 512, 0, stream>>>(patches, projwt, proj_b, pe, hb, PROWS, ND, ND,
                                                ND, 6);
  cls_kernel<<<(NB * ND + 255) / 256, 256, 0, stream>>>(cls_w, pe, hb);

  for (int l = 0; l < NLAY; ++l) {
    size_t wo = (size_t)l * ND * ND;
    transpose_layer<<<1584, 512, 0, stream>>>(Wq + wo, Wk + wo, Wv + wo,
                                              fc1_w + (size_t)l * ND * NDFF,
                                              fc2_w + (size_t)l * NDFF * ND, wqkvt, fc1t, fc2t);
    gemm2<1><<<dim3(450, 1, 1), 512, 0, stream>>>(hb, wqkvt, nullptr, nullptr, qkvb, NROWS, NQKV,
                                                  ND, ND, 18);
    attn_kernel<<<dim3(NB, NHD), 256, 0, stream>>>(qkvb, att);
    ln_kernel<<<NROWS, 384, 0, stream>>>(hb, att, ln1_g + l * ND, ln1_b + l * ND, h1b);
    gemm2<2><<<dim3(600, 1, 1), 512, 0, stream>>>(h1b, fc1t, fc1_b + l * NDFF, nullptr, ffb,
                                                  NROWS, NDFF, ND, ND, 24);
    gemm2<4><<<dim3(150, 1, 3), 512, 0, stream>>>(ffb, fc2t, nullptr, nullptr, parts, NROWS, ND,
                                                  1024, NDFF, 6);
    ln_fuse2<<<NROWS, 384, 0, stream>>>(h1b, parts, fc2_b + l * ND, ln2_g + l * ND, ln2_b + l * ND,
                                        hb);
  }
  outcopy_kernel<<<(NB * ND + 255) / 256, 256, 0, stream>>>(hb, (float*)d_out);
}

// Round 10
// 2107.507 us; speedup vs baseline: 1.2867x; 1.0526x over previous
//
#include <hip/hip_runtime.h>

typedef unsigned short u16;
typedef unsigned int u32;
typedef __bf16 bf16x8 __attribute__((ext_vector_type(8)));
typedef float f32x4 __attribute__((ext_vector_type(4)));
typedef u16 u16x8 __attribute__((ext_vector_type(8)));

#define NB 32
#define ND 768
#define NTOK 197
#define NROWS (NB * NTOK)   /* 6304 */
#define NPATCH 196
#define PROWS (NB * NPATCH) /* 6272 */
#define NHD 12
#define NDFF 3072
#define NLAY 12
#define NQKV 2304

// RNE float->bf16
static __device__ __forceinline__ u16 f2b(float f) {
  u32 u = __builtin_bit_cast(u32, f);
  u32 r = u + 0x7FFFu + ((u >> 16) & 1u);
  return (u16)(r >> 16);
}
static __device__ __forceinline__ float b2f(u16 u) {
  u32 x = ((u32)u) << 16;
  return __builtin_bit_cast(float, x);
}

static __device__ __forceinline__ float wsum(float v) {
#pragma unroll
  for (int off = 32; off > 0; off >>= 1) v += __shfl_xor(v, off);
  return v;
}

static __device__ __forceinline__ void stage16(const u16* g, u16* l) {
  __builtin_amdgcn_global_load_lds((const __attribute__((address_space(1))) void*)g,
                                   (__attribute__((address_space(3))) void*)l, 16, 0, 0);
}

// ---------------- positional encoding table [197][768] ----------------
__global__ void pe_kernel(float* __restrict__ pe) {
  int idx = blockIdx.x * 256 + threadIdx.x;
  if (idx >= NTOK * ND) return;
  int t = idx / ND, d = idx % ND;
  int i = d & ~1;
  float e = (2.0f * (float)i) / (float)ND;
  float denom = powf(10000.0f, e);
  float ang = (float)t / denom;
  pe[idx] = (d & 1) ? cosf(ang) : sinf(ang);
}

// ------- BN + unfold-order patchify -> bf16 [6272][768], 8 px/thread ---
__global__ void patch_kernel(const float* __restrict__ x,
                             const float* __restrict__ bng, const float* __restrict__ bnb,
                             const float* __restrict__ bnm, const float* __restrict__ bnv,
                             u16* __restrict__ out) {
  int idx = blockIdx.x * 256 + threadIdx.x;
  if (idx >= PROWS * 96) return;
  int row = idx / 96, c8 = (idx % 96) * 8;
  int b = row / NPATCH, s = row % NPATCH;
  int ph = s / 14, pw = s % 14;
  int c = c8 / 256, rr = c8 % 256;
  int py = rr / 16, px0 = rr % 16;  // 0 or 8
  const float* xp =
      x + (((size_t)(b * 3 + c) * 224) + ph * 16 + py) * 224 + pw * 16 + px0;
  float scale = rsqrtf(bnv[c] + 1e-5f) * bng[c];
  float sub = bnm[c], add = bnb[c];
  u16x8 o;
#pragma unroll
  for (int j = 0; j < 8; j++) o[j] = f2b((xp[j] - sub) * scale + add);
  *reinterpret_cast<u16x8*>(out + (size_t)idx * 8) = o;
}

// ---------------- cls token row (t=0) + pe[0], bf16 trunk --------------
__global__ void cls_kernel(const float* __restrict__ cls_w, const float* __restrict__ pe,
                           u16* __restrict__ hb) {
  int idx = blockIdx.x * 256 + threadIdx.x;
  if (idx >= NB * ND) return;
  int b = idx / ND, d = idx % ND;
  hb[(size_t)(b * NTOK) * ND + d] = f2b(cls_w[d] + pe[d]);
}

// ---------------- fp32 [R][C] -> bf16 [C][R] transpose-convert ---------
__global__ __launch_bounds__(256) void transpose_cvt(const float* __restrict__ src,
                                                     u16* __restrict__ dst, int R, int C) {
  __shared__ float tile[32][33];
  int tx = threadIdx.x, ty = threadIdx.y;
  int c0 = blockIdx.x * 32, r0 = blockIdx.y * 32;
#pragma unroll
  for (int i = ty; i < 32; i += 8) {
    int r = r0 + i, c = c0 + tx;
    tile[i][tx] = (r < R && c < C) ? src[(size_t)r * C + c] : 0.f;
  }
  __syncthreads();
#pragma unroll
  for (int i = ty; i < 32; i += 8) {
    int c = c0 + i, r = r0 + tx;
    if (r < R && c < C) dst[(size_t)c * R + r] = f2b(tile[tx][i]);
  }
}

// ---- transpose body: one 64x64 tile of the 5 per-layer weights --------
// idx in [0,1584): [0,432) qkv 12x12x3; [432,1008) fc1 12x48; [1008,1584) fc2 48x12
static __device__ __forceinline__ void transpose_body(
    int idx, const float* __restrict__ Wq, const float* __restrict__ Wk,
    const float* __restrict__ Wv, const float* __restrict__ f1, const float* __restrict__ f2,
    u16* __restrict__ wqkvt, u16* __restrict__ fc1t, u16* __restrict__ fc2t, void* smemraw,
    int tid) {
  const float* src;
  u16* dst;
  int C, R, rt, ct;
  if (idx < 432) {
    int z = idx / 144, loc = idx % 144;
    src = z == 0 ? Wq : (z == 1 ? Wk : Wv);
    dst = wqkvt + (size_t)z * ND * ND;
    R = 768; C = 768; rt = loc / 12; ct = loc % 12;
  } else if (idx < 1008) {
    int loc = idx - 432;
    src = f1; dst = fc1t; R = 768; C = 3072; rt = loc / 48; ct = loc % 48;
  } else {
    int loc = idx - 1008;
    src = f2; dst = fc2t; R = 3072; C = 768; rt = loc / 12; ct = loc % 12;
  }
  float(*tile)[65] = (float(*)[65])smemraw;
  const int l2 = tid & 31, rp = tid >> 5;  // 0..15
  const int r0 = rt * 64, c0 = ct * 64;
#pragma unroll
  for (int i = rp; i < 64; i += 16) {
    float2 v = *reinterpret_cast<const float2*>(src + (size_t)(r0 + i) * C + c0 + l2 * 2);
    tile[i][l2 * 2] = v.x;
    tile[i][l2 * 2 + 1] = v.y;
  }
  __syncthreads();
#pragma unroll
  for (int j = rp; j < 64; j += 16) {
    u32 o = (u32)f2b(tile[l2 * 2][j]) | ((u32)f2b(tile[l2 * 2 + 1][j]) << 16);
    *reinterpret_cast<u32*>(dst + (size_t)(c0 + j) * R + r0 + l2 * 2) = o;
  }
}

// standalone (layer 0 prologue)
__global__ __launch_bounds__(512) void transpose_layer(
    const float* __restrict__ Wq, const float* __restrict__ Wk, const float* __restrict__ Wv,
    const float* __restrict__ f1, const float* __restrict__ f2,
    u16* __restrict__ wqkvt, u16* __restrict__ fc1t, u16* __restrict__ fc2t) {
  __shared__ float tile[64][65];
  transpose_body(blockIdx.x, Wq, Wk, Wv, f1, f2, wqkvt, fc1t, fc2t, tile, threadIdx.x);
}

// ======== 256x128 bf16 bt-GEMM, BK=32, 3 LDS bufs, 2 blocks/CU =========
// TR=true: blocks >= ngx run next-layer weight transposes instead (fused
// independent work riding in the same dispatch).
// MODE 0: +bias +pe patch scatter | 1: bf16 | 2: +bias ReLU bf16
// MODE 4: bf16 out at z-offset (split-K partials)
template <int MODE, bool TR>
__global__ __launch_bounds__(512, 4) void gemm2(
    const u16* __restrict__ A, const u16* __restrict__ Bt, const float* __restrict__ bias,
    const float* __restrict__ pe, u16* __restrict__ Cb, int M, int N, int K, int lda, int nby,
    int ngx, const float* __restrict__ tWq, const float* __restrict__ tWk,
    const float* __restrict__ tWv, const float* __restrict__ tf1, const float* __restrict__ tf2,
    u16* __restrict__ twqkv, u16* __restrict__ tfc1, u16* __restrict__ tfc2) {
  __shared__ u16 smem[36864];  // 3 x 12288 elems (A 8192 + B 4096); transpose tile alias
  if (TR && (int)blockIdx.x >= ngx) {
    transpose_body(blockIdx.x - ngx, tWq, tWk, tWv, tf1, tf2, twqkv, tfc1, tfc2, smem,
                   threadIdx.x);
    return;
  }
  const int tid = threadIdx.x;
  const int w = tid >> 6, l = tid & 63;
  const int lr = l & 15, lg = l >> 4;
  const int wr = w >> 1, wc = w & 1;

  const int nwg = ngx;
  const int q8 = nwg >> 3, r8 = nwg & 7;
  const int xcd = blockIdx.x & 7, sidx = blockIdx.x >> 3;
  const int swz = (xcd < r8 ? xcd * (q8 + 1) : r8 * (q8 + 1) + (xcd - r8) * q8) + sidx;
  const int m0 = (swz / nby) * 256, n0 = (swz % nby) * 128;

  A += (size_t)blockIdx.z * K;
  Bt += (size_t)blockIdx.z * K;

  const int srow = l >> 2;
  const int scol = (((l & 3) ^ ((l >> 2) & 3) ^ ((l >> 4) & 3))) * 8;
  int raA0 = m0 + 32 * w + srow;
  int raA1 = raA0 + 16;
  raA0 = raA0 < M ? raA0 : M - 1;
  raA1 = raA1 < M ? raA1 : M - 1;
  const int rbB = n0 + 16 * w + srow;
  const u16* pA0 = A + (size_t)raA0 * lda + scol;
  const u16* pA1 = A + (size_t)raA1 * lda + scol;
  const u16* pB = Bt + (size_t)rbB * lda + scol;
  const int dsgA0 = (2 * w) * 512;
  const int dsgA1 = (2 * w + 1) * 512;
  const int dsgB = 8192 + w * 512;

  const int xo = ((lg ^ (lr & 3) ^ ((lr >> 2) & 3))) * 8;
  const int aoff = (wr * 64 + lr) * 32 + xo;
  const int boff = 8192 + (wc * 64 + lr) * 32 + xo;

  f32x4 acc[4][4] = {};
  const int nk = K >> 5;

#define BARF                           \
  {                                    \
    __builtin_amdgcn_sched_barrier(0); \
    __builtin_amdgcn_s_barrier();      \
    asm volatile("" ::: "memory");     \
    __builtin_amdgcn_sched_barrier(0); \
  }
#define VMW(N) asm volatile("s_waitcnt vmcnt(" #N ")" ::: "memory");

  stage16(pA0, smem + dsgA0);
  stage16(pA1, smem + dsgA1);
  stage16(pB, smem + dsgB);
  stage16(pA0 + 32, smem + 12288 + dsgA0);
  stage16(pA1 + 32, smem + 12288 + dsgA1);
  stage16(pB + 32, smem + 12288 + dsgB);
  VMW(3);
  BARF;

  int cur = 0;
  for (int t = 0; t < nk; ++t) {
    const u16* sb = smem + cur * 12288;
    int c2 = cur + 2;
    if (c2 >= 3) c2 -= 3;
    const bool more2 = (t + 2) < nk;
    if (more2) {
      u16* db = smem + c2 * 12288;
      const int ko = (t + 2) * 32;
      stage16(pA0 + ko, db + dsgA0);
      stage16(pA1 + ko, db + dsgA1);
      stage16(pB + ko, db + dsgB);
    }
    bf16x8 ar[4], br[4];
#pragma unroll
    for (int n = 0; n < 4; ++n) br[n] = *(const bf16x8*)(sb + boff + n * 512);
#pragma unroll
    for (int m = 0; m < 4; ++m) ar[m] = *(const bf16x8*)(sb + aoff + m * 512);
    __builtin_amdgcn_s_setprio(1);
#pragma unroll
    for (int m = 0; m < 4; ++m) {
#pragma unroll
      for (int n = 0; n < 4; ++n)
        acc[m][n] = __builtin_amdgcn_mfma_f32_16x16x32_bf16(ar[m], br[n], acc[m][n], 0, 0, 0);
    }
    __builtin_amdgcn_s_setprio(0);
    if (more2) {
      VMW(3);
    } else if (t + 1 < nk) {
      VMW(0);
    }
    if (t + 1 < nk) BARF;
    cur = cur == 2 ? 0 : cur + 1;
  }

  // ---- epilogue ----
  const size_t zoff = (size_t)blockIdx.z * (size_t)M * (size_t)N;
#pragma unroll
  for (int m = 0; m < 4; ++m) {
    const int rowb = m0 + wr * 64 + m * 16 + lg * 4;
#pragma unroll
    for (int n = 0; n < 4; ++n) {
      const int col = n0 + wc * 64 + n * 16 + lr;
      float bval = (MODE == 0 || MODE == 2) ? bias[col] : 0.f;
#pragma unroll
      for (int r = 0; r < 4; ++r) {
        const int row = rowb + r;
        if (row < M) {
          float v = acc[m][n][r] + bval;
          if (MODE == 2) v = fmaxf(v, 0.f);
          if (MODE == 0) {
            int b = row / NPATCH, t = 1 + row % NPATCH;
            float val = v + pe[(size_t)t * ND + col];
            Cb[(size_t)(b * NTOK + t) * ND + col] = f2b(val);
          } else if (MODE == 4) {
            Cb[zoff + (size_t)row * N + col] = f2b(v);
          } else {
            Cb[(size_t)row * N + col] = f2b(v);
          }
        }
      }
    }
  }
}

// ---------------- fused MHA: one block per (b, head), bf16 out ---------
__global__ __launch_bounds__(256) void attn_kernel(const u16* __restrict__ qkv,
                                                   u16* __restrict__ att) {
  const int b = blockIdx.x, h = blockIdx.y;
  const int tid = threadIdx.x;
  const int wave = tid >> 6, lane = tid & 63;
  const int lr = lane & 15, lg = lane >> 4;
  __shared__ u16 Vt[64][232];
  __shared__ u16 Pl[4][16][232];

  const size_t bbase = (size_t)(b * NTOK) * NQKV + h * 64;

  // stage V^T: vectorized 16B global reads, scalar LDS scatter
  for (int idx = tid; idx < NTOK * 8; idx += 256) {
    int k2 = idx >> 3, d0 = (idx & 7) * 8;
    u16x8 v = *reinterpret_cast<const u16x8*>(qkv + bbase + (size_t)k2 * NQKV + 1536 + d0);
#pragma unroll
    for (int j = 0; j < 8; j++) Vt[d0 + j][k2] = v[j];
  }
  for (int idx = tid; idx < 64 * 35; idx += 256) {
    int d = idx / 35, k2 = 197 + idx % 35;
    Vt[d][k2] = 0;
  }
  for (int idx = tid; idx < 4 * 16 * 24; idx += 256) {
    int w = idx / (16 * 24), rr = (idx / 24) % 16, c = 208 + idx % 24;
    Pl[w][rr][c] = 0;
  }
  __syncthreads();

  for (int mt = wave; mt < 13; mt += 4) {
    int qrow = mt * 16 + lr;
    if (qrow > 196) qrow = 196;
    bf16x8 af[2];
#pragma unroll
    for (int ks = 0; ks < 2; ks++)
      af[ks] =
          *reinterpret_cast<const bf16x8*>(qkv + bbase + (size_t)qrow * NQKV + ks * 32 + lg * 8);

    f32x4 sf[13];
#pragma unroll
    for (int nt = 0; nt < 13; nt++) {
      int krow = nt * 16 + lr;
      if (krow > 196) krow = 196;
      f32x4 z = {0.f, 0.f, 0.f, 0.f};
#pragma unroll
      for (int ks = 0; ks < 2; ks++) {
        bf16x8 bf_ = *reinterpret_cast<const bf16x8*>(qkv + bbase + (size_t)krow * NQKV + 768 +
                                                      ks * 32 + lg * 8);
        z = __builtin_amdgcn_mfma_f32_16x16x32_bf16(af[ks], bf_, z, 0, 0, 0);
      }
      sf[nt] = z;
    }

    float sm[4];
#pragma unroll
    for (int r = 0; r < 4; r++) {
      float mx = -1e30f;
#pragma unroll
      for (int nt = 0; nt < 13; nt++) {
        int col = nt * 16 + lr;
        float val = (col < NTOK) ? sf[nt][r] * 0.125f : -1e30f;
        sf[nt][r] = val;
        mx = fmaxf(mx, val);
      }
#pragma unroll
      for (int off = 1; off < 16; off <<= 1) mx = fmaxf(mx, __shfl_xor(mx, off));
      float sum = 0.f;
#pragma unroll
      for (int nt = 0; nt < 13; nt++) {
        float pv = __expf(sf[nt][r] - mx);
        sum += pv;
        Pl[wave][lg * 4 + r][nt * 16 + lr] = f2b(pv);
      }
#pragma unroll
      for (int off = 1; off < 16; off <<= 1) sum += __shfl_xor(sum, off);
      sm[r] = sum;
    }

#pragma unroll
    for (int dt = 0; dt < 4; dt++) {
      f32x4 o = {0.f, 0.f, 0.f, 0.f};
#pragma unroll
      for (int ks = 0; ks < 7; ks++) {
        bf16x8 pa = *reinterpret_cast<const bf16x8*>(&Pl[wave][lr][ks * 32 + lg * 8]);
        bf16x8 vv = *reinterpret_cast<const bf16x8*>(&Vt[dt * 16 + lr][ks * 32 + lg * 8]);
        o = __builtin_amdgcn_mfma_f32_16x16x32_bf16(pa, vv, o, 0, 0, 0);
      }
#pragma unroll
      for (int r = 0; r < 4; r++) {
        int q = mt * 16 + lg * 4 + r;
        if (q < NTOK)
          att[(size_t)b * (NTOK * ND) + ((size_t)(h * NTOK + q)) * 64 + dt * 16 + lr] =
              f2b(o[r] / sm[r]);
      }
    }
  }
}

// ---- LayerNorm( trunk + att ), wave-per-row (4 rows / 256-thr block) --
__global__ __launch_bounds__(256) void ln_kernel(const u16* __restrict__ xa,
                                                 const u16* __restrict__ xb,
                                                 const float* __restrict__ gw,
                                                 const float* __restrict__ bw,
                                                 u16* __restrict__ yb) {
  int row = blockIdx.x * 4 + (threadIdx.x >> 6);
  int lane = threadIdx.x & 63;
  size_t base = (size_t)row * 384;  // u32 units
  float v0[6], v1[6];
  float s = 0.f;
#pragma unroll
  for (int i = 0; i < 6; i++) {
    size_t j = base + lane + 64 * i;
    u32 aa = reinterpret_cast<const u32*>(xa)[j];
    u32 bb = reinterpret_cast<const u32*>(xb)[j];
    v0[i] = b2f((u16)(aa & 0xffff)) + b2f((u16)(bb & 0xffff));
    v1[i] = b2f((u16)(aa >> 16)) + b2f((u16)(bb >> 16));
    s += v0[i] + v1[i];
  }
  s = wsum(s);
  float mean = s * (1.f / 768.f);
  float q = 0.f;
#pragma unroll
  for (int i = 0; i < 6; i++) {
    float d0 = v0[i] - mean, d1 = v1[i] - mean;
    q += d0 * d0 + d1 * d1;
  }
  q = wsum(q);
  float inv = rsqrtf(q * (1.f / 768.f) + 1e-5f);
#pragma unroll
  for (int i = 0; i < 6; i++) {
    int j = lane + 64 * i;
    float2 g = reinterpret_cast<const float2*>(gw)[j];
    float2 bb = reinterpret_cast<const float2*>(bw)[j];
    float o0 = (v0[i] - mean) * inv * g.x + bb.x;
    float o1 = (v1[i] - mean) * inv * g.y + bb.y;
    reinterpret_cast<u32*>(yb)[base + j] = (u32)f2b(o0) | ((u32)f2b(o1) << 16);
  }
}

// -- LayerNorm( h1b + sum3(parts) + fc2_bias ), wave-per-row ------------
__global__ __launch_bounds__(256) void ln_fuse2(const u16* __restrict__ h1b,
                                                const u16* __restrict__ parts,
                                                const float* __restrict__ fb,
                                                const float* __restrict__ gw,
                                                const float* __restrict__ bw,
                                                u16* __restrict__ yb) {
  const size_t PS2 = (size_t)NROWS * ND / 2;  // u32 units per part
  int row = blockIdx.x * 4 + (threadIdx.x >> 6);
  int lane = threadIdx.x & 63;
  size_t base = (size_t)row * 384;
  float v0[6], v1[6];
  float s = 0.f;
#pragma unroll
  for (int i = 0; i < 6; i++) {
    size_t j = base + lane + 64 * i;
    u32 aa = reinterpret_cast<const u32*>(h1b)[j];
    const u32* pp = reinterpret_cast<const u32*>(parts);
    u32 q0 = pp[j], q1 = pp[PS2 + j], q2 = pp[2 * PS2 + j];
    float2 fbv = reinterpret_cast<const float2*>(fb)[lane + 64 * i];
    v0[i] = b2f((u16)(aa & 0xffff)) + b2f((u16)(q0 & 0xffff)) + b2f((u16)(q1 & 0xffff)) +
            b2f((u16)(q2 & 0xffff)) + fbv.x;
    v1[i] = b2f((u16)(aa >> 16)) + b2f((u16)(q0 >> 16)) + b2f((u16)(q1 >> 16)) +
            b2f((u16)(q2 >> 16)) + fbv.y;
    s += v0[i] + v1[i];
  }
  s = wsum(s);
  float mean = s * (1.f / 768.f);
  float q = 0.f;
#pragma unroll
  for (int i = 0; i < 6; i++) {
    float d0 = v0[i] - mean, d1 = v1[i] - mean;
    q += d0 * d0 + d1 * d1;
  }
  q = wsum(q);
  float inv = rsqrtf(q * (1.f / 768.f) + 1e-5f);
#pragma unroll
  for (int i = 0; i < 6; i++) {
    int j = lane + 64 * i;
    float2 g = reinterpret_cast<const float2*>(gw)[j];
    float2 bb = reinterpret_cast<const float2*>(bw)[j];
    float o0 = (v0[i] - mean) * inv * g.x + bb.x;
    float o1 = (v1[i] - mean) * inv * g.y + bb.y;
    reinterpret_cast<u32*>(yb)[base + j] = (u32)f2b(o0) | ((u32)f2b(o1) << 16);
  }
}

__global__ void outcopy_kernel(const u16* __restrict__ hb, float* __restrict__ out) {
  int idx = blockIdx.x * 256 + threadIdx.x;
  if (idx >= NB * ND) return;
  int b = idx / ND, d = idx % ND;
  out[idx] = b2f(hb[(size_t)(b * NTOK) * ND + d]);
}

extern "C" void kernel_launch(void* const* d_in, const int* in_sizes, int n_in, void* d_out,
                              int out_size, void* d_ws, size_t ws_size, hipStream_t stream) {
  const float* x = (const float*)d_in[0];
  const float* bng = (const float*)d_in[1];
  const float* bnb = (const float*)d_in[2];
  const float* bnm = (const float*)d_in[3];
  const float* bnv = (const float*)d_in[4];
  const float* proj_w = (const float*)d_in[5];
  const float* proj_b = (const float*)d_in[6];
  const float* cls_w = (const float*)d_in[7];
  const float* Wq = (const float*)d_in[8];
  const float* Wk = (const float*)d_in[9];
  const float* Wv = (const float*)d_in[10];
  const float* fc1_w = (const float*)d_in[11];
  const float* fc1_b = (const float*)d_in[12];
  const float* fc2_w = (const float*)d_in[13];
  const float* fc2_b = (const float*)d_in[14];
  const float* ln1_g = (const float*)d_in[15];
  const float* ln1_b = (const float*)d_in[16];
  const float* ln2_g = (const float*)d_in[17];
  const float* ln2_b = (const float*)d_in[18];

  char* wp = (char*)d_ws;
  auto carve = [&](size_t bytes) -> char* {
    char* r = wp;
    wp += (bytes + 255) & ~(size_t)255;
    return r;
  };
  float* pe = (float*)carve((size_t)NTOK * ND * 4);
  u16* patches = (u16*)carve((size_t)PROWS * ND * 2);
  u16* projwt = (u16*)carve((size_t)ND * ND * 2);
  u16* wqkvt[2] = {(u16*)carve((size_t)NQKV * ND * 2), (u16*)carve((size_t)NQKV * ND * 2)};
  u16* fc1t[2] = {(u16*)carve((size_t)ND * NDFF * 2), (u16*)carve((size_t)ND * NDFF * 2)};
  u16* fc2t[2] = {(u16*)carve((size_t)ND * NDFF * 2), (u16*)carve((size_t)ND * NDFF * 2)};
  u16* hb = (u16*)carve((size_t)NROWS * ND * 2);
  u16* h1b = (u16*)carve((size_t)NROWS * ND * 2);
  // union: qkvb (29 MB, dead after attn) and fc2 bf16 split-K partials (29 MB)
  char* uni = carve(3 * (size_t)NROWS * ND * 2);
  u16* qkvb = (u16*)uni;
  u16* parts = (u16*)uni;
  u16* att = (u16*)carve((size_t)NROWS * ND * 2);
  u16* ffb = (u16*)carve((size_t)NROWS * NDFF * 2);
  if ((size_t)(wp - (char*)d_ws) > ws_size) return;

  pe_kernel<<<(NTOK * ND + 255) / 256, 256, 0, stream>>>(pe);
  patch_kernel<<<(PROWS * 96 + 255) / 256, 256, 0, stream>>>(x, bng, bnb, bnm, bnv, patches);
  transpose_cvt<<<dim3(24, 24), dim3(32, 8), 0, stream>>>(proj_w, projwt, ND, ND);
  gemm2<0, false><<<dim3(150, 1, 1), 512, 0, stream>>>(
      patches, projwt, proj_b, pe, hb, PROWS, ND, ND, ND, 6, 150, nullptr, nullptr, nullptr,
      nullptr, nullptr, nullptr, nullptr, nullptr);
  cls_kernel<<<(NB * ND + 255) / 256, 256, 0, stream>>>(cls_w, pe, hb);
  // layer 0 weight transposes (standalone)
  transpose_layer<<<1584, 512, 0, stream>>>(Wq, Wk, Wv, fc1_w, fc2_w, wqkvt[0], fc1t[0],
                                            fc2t[0]);

  for (int l = 0; l < NLAY; ++l) {
    const int cur = l & 1, nxt = cur ^ 1;
    const bool more = l + 1 < NLAY;
    size_t nwo = (size_t)(l + 1) * ND * ND;
    size_t nfo = (size_t)(l + 1) * ND * NDFF;
    // qkv GEMM + (fused) next-layer weight transposes
    gemm2<1, true><<<dim3(450 + (more ? 1584 : 0), 1, 1), 512, 0, stream>>>(
        hb, wqkvt[cur], nullptr, nullptr, qkvb, NROWS, NQKV, ND, ND, 18, 450,
        more ? Wq + nwo : nullptr, more ? Wk + nwo : nullptr, more ? Wv + nwo : nullptr,
        more ? fc1_w + nfo : nullptr, more ? fc2_w + nfo : nullptr, wqkvt[nxt], fc1t[nxt],
        fc2t[nxt]);
    attn_kernel<<<dim3(NB, NHD), 256, 0, stream>>>(qkvb, att);
    ln_kernel<<<NROWS / 4, 256, 0, stream>>>(hb, att, ln1_g + l * ND, ln1_b + l * ND, h1b);
    gemm2<2, false><<<dim3(600, 1, 1), 512, 0, stream>>>(
        h1b, fc1t[cur], fc1_b + l * NDFF, nullptr, ffb, NROWS, NDFF, ND, ND, 24, 600, nullptr,
        nullptr, nullptr, nullptr, nullptr, nullptr, nullptr, nullptr);
    gemm2<4, false><<<dim3(150, 1, 3), 512, 0, stream>>>(
        ffb, fc2t[cur], nullptr, nullptr, parts, NROWS, ND, 1024, NDFF, 6, 150, nullptr, nullptr,
        nullptr, nullptr, nullptr, nullptr, nullptr, nullptr);
    ln_fuse2<<<NROWS / 4, 256, 0, stream>>>(h1b, parts, fc2_b + l * ND, ln2_g + l * ND,
                                            ln2_b + l * ND, hb);
  }
  outcopy_kernel<<<(NB * ND + 255) / 256, 256, 0, stream>>>(hb, (float*)d_out);
}